// Round 12
// baseline (873.357 us; speedup 1.0000x reference)
//
#include <hip/hip_runtime.h>
#include <hip/hip_bf16.h>

#define B8 8
#define KNN 32
typedef unsigned short u16;
typedef unsigned int u32;
typedef unsigned long long u64;

typedef __attribute__((ext_vector_type(8))) _Float16 half8;
typedef __attribute__((ext_vector_type(4))) float f32x4;

static __device__ __forceinline__ u16 f2h_u(float f) {
  _Float16 h = (_Float16)f; u16 u; __builtin_memcpy(&u, &h, 2); return u;
}

// monotonic (distance, id) -> u64 key
static __device__ __forceinline__ u64 enc_key(float d, int id) {
  u32 u = __float_as_uint(d);
  u = (d >= 0.f) ? (u | 0x80000000u) : ~u;
  return ((u64)u << 32) | (u32)id;
}
static __device__ __forceinline__ float dec_val(u64 k) {
  u32 u = (u32)(k >> 32);
  u = (u & 0x80000000u) ? (u & 0x7fffffffu) : ~u;
  return __uint_as_float(u);
}

// rank-redistribute 64 keys (one per lane) -> sorted across lanes; sets tau = 32nd
static __device__ __forceinline__ u64 rank64(u64 mk, int lane, u64* slk, u64* outk, float& tau) {
  slk[lane] = mk;
  int r = 0;
#pragma unroll 16
  for (int j = 0; j < 64; ++j) r += (slk[j] < mk) ? 1 : 0;
  outk[r] = mk;
  u64 res = outk[lane];
  tau = dec_val(outk[31]);
  return res;
}

// per-block BN finalize from 16-shadow sums (bitwise identical to prior bn_finalize)
static __device__ __forceinline__ void bn_from_red(int o, const float* red_s, const float* red_q,
                                                   const float* g, const float* be, float invcnt,
                                                   float* scs, float* shs) {
  float s = 0.f, q = 0.f;
#pragma unroll
  for (int i = 0; i < 16; ++i) { s += red_s[i * 256 + o]; q += red_q[i * 256 + o]; }
  float mu  = s * invcnt;
  float var = fmaxf(q * invcnt - mu * mu, 0.f);
  float scv = g[o] * rsqrtf(var + 1e-5f);
  scs[o] = scv;
  shs[o] = fmaf(-mu, scv, be[o]);
}

// ---------------- KNN: 2 queries/block, 2 waves/query (each scans half of each tile) ----------------
__global__ __launch_bounds__(256) void knn_kernel(const float* __restrict__ pcd,
                                                  int N, int M, int* __restrict__ idxout) {
  __shared__ float4 pts[1024];
  __shared__ u64 bufk[4][32];
  __shared__ u64 slk[4][64];
  __shared__ u64 outk[4][64];
  __shared__ float taus[4];
  __shared__ u64 mergek[2][32];
  const int t = threadIdx.x;
  const int lane = t & 63, w = t >> 6;
  const int q = w >> 1, h = w & 1;
  const int b = blockIdx.y;
  const int m = blockIdx.x * 2 + q;
  const float* base = pcd + (size_t)b * 12288;
  const float qx = base[m*3], qy = base[m*3+1], qz = base[m*3+2];
  const float ax = -2.f*qx, ay = -2.f*qy, az = -2.f*qz;

  u64 heldk; float tau; int cnt = 0;

  for (int i = t; i < 1024; i += 256) {
    const float* p = base + (size_t)i * 3;
    float x = p[0], y = p[1], z = p[2];
    pts[i] = make_float4(x, y, z, x*x + y*y + z*z);
  }
  __syncthreads();

  // init: rank-sort first 64 candidates of this wave's half
  {
    float4 p = pts[h * 512 + lane];
    float r0 = fmaf(ax, p.x, fmaf(ay, p.y, fmaf(az, p.z, p.w)));
    heldk = rank64(enc_key(r0, h * 512 + lane), lane, slk[w], outk[w], tau);
  }

  for (int n0 = 0; n0 < N; n0 += 1024) {
    if (n0) {
      taus[w] = tau;
      __syncthreads();
      for (int i = t; i < 1024; i += 256) {
        const float* p = base + (size_t)(n0 + i) * 3;
        float x = p[0], y = p[1], z = p[2];
        pts[i] = make_float4(x, y, z, x*x + y*y + z*z);
      }
      __syncthreads();
      tau = fminf(tau, taus[w ^ 1]);     // partner wave's tau is a safe filter
    }
    for (int cc = 0; cc < 512; cc += 256) {
      const int c = h * 512 + cc;
      float4 p0 = pts[c + lane];
      float4 p1 = pts[c + 64 + lane];
      float4 p2 = pts[c + 128 + lane];
      float4 p3 = pts[c + 192 + lane];
      float r[4];
      r[0] = fmaf(ax, p0.x, fmaf(ay, p0.y, fmaf(az, p0.z, p0.w)));
      r[1] = fmaf(ax, p1.x, fmaf(ay, p1.y, fmaf(az, p1.z, p1.w)));
      r[2] = fmaf(ax, p2.x, fmaf(ay, p2.y, fmaf(az, p2.z, p2.w)));
      r[3] = fmaf(ax, p3.x, fmaf(ay, p3.y, fmaf(az, p3.z, p3.w)));
      if (n0 == 0 && cc == 0) r[0] = 3.4e38f;   // init consumed this batch
      float rmn = fminf(fminf(r[0], r[1]), fminf(r[2], r[3]));
      if (!__any(rmn < tau)) continue;
#pragma unroll
      for (int j = 0; j < 4; ++j) {
        float rr = r[j];
        if (!__any(rr < tau)) continue;
        int gid = n0 + c + j * 64 + lane;
        bool pass = rr < tau;
        while (__any(pass)) {
          u64 mk_ = __ballot(pass);
          int before = __popcll(mk_ & ((1ull << lane) - 1ull));
          int total  = __popcll(mk_);
          int room = 32 - cnt;
          if (pass && before < room) {
            bufk[w][cnt + before] = enc_key(rr, gid);
            pass = false;
          }
          if (total >= room) {
            u64 mk = (lane < 32) ? heldk : bufk[w][lane - 32];
            heldk = rank64(mk, lane, slk[w], outk[w], tau);
            cnt = 0;
            pass = pass && (rr < tau);
          } else {
            cnt += total;
          }
        }
      }
    }
  }
  if (cnt > 0) {
    int bl = lane - 32;
    u64 mk = (lane < 32) ? heldk
             : ((bl < cnt) ? bufk[w][bl]
                           : ((0xFFFFFFFFull << 32) | (0xFFFFFF00u | (u32)lane)));
    heldk = rank64(mk, lane, slk[w], outk[w], tau);
  }
  // merge the two halves of each query
  if (h == 1 && lane < 32) mergek[q][lane] = heldk;
  __syncthreads();
  if (h == 0) {
    u64 mk = (lane < 32) ? heldk : mergek[q][lane - 32];
    heldk = rank64(mk, lane, slk[w], outk[w], tau);
    if (lane < 32) idxout[((size_t)b * M + m) * KNN + lane] = (int)(u32)(heldk & 0xFFFFFFFFu);
  }
}

// ---------------- prep_all ----------------
__global__ void prep_all(
    const float* __restrict__ W1a, const float* __restrict__ W1b,
    const float* __restrict__ W2a, const float* __restrict__ W2b,
    const float* __restrict__ W3a, const float* __restrict__ W3b,
    float* __restrict__ RED,
    float* __restrict__ WAT1, float* __restrict__ WBT1, u16* __restrict__ WBH1,
    float* __restrict__ WBT2, u16* __restrict__ WAH2, u16* __restrict__ WBH2,
    float* __restrict__ WBT3, u16* __restrict__ WAH3, u16* __restrict__ WBH3)
{
  int i0 = blockIdx.x * 256 + threadIdx.x;
  int NT = gridDim.x * 256;
  for (int i = i0; i < 49152; i += NT) RED[i] = 0.f;     // 6 RED buffers
  for (int i = i0; i < 256; i += NT) {
    int c = i >> 6, o = i & 63;
    float w1 = (c < 3) ? W1a[o*6 + c] : 0.f;
    float w2 = (c < 3) ? W1a[o*6 + 3 + c] : 0.f;
    WAT1[i] = w1; WBT1[i] = w2 - w1;
  }
  for (int i = i0; i < 4096; i += NT) WBH1[i] = f2h_u(W1b[i]);
  for (int i = i0; i < 68*128; i += NT) {
    int c = i >> 7, o = i & 127;
    float w1 = 0.f, w2 = 0.f;
    if (c < 67) { w1 = W2a[o*134 + c]; w2 = W2a[o*134 + 67 + c]; }
    WBT2[i] = w2 - w1;
  }
  for (int i = i0; i < 128*128; i += NT) {
    int o = i >> 7, k = i & 127;
    WAH2[i] = (k < 67) ? f2h_u(W2a[o*134 + k]) : (u16)0;
  }
  for (int i = i0; i < 16384; i += NT) WBH2[i] = f2h_u(W2b[i]);
  for (int i = i0; i < 132*256; i += NT) {
    int c = i >> 8, o = i & 255;
    float w1 = 0.f, w2 = 0.f;
    if (c < 131) { w1 = W3a[o*262 + c]; w2 = W3a[o*262 + 131 + c]; }
    WBT3[i] = w2 - w1;
  }
  for (int i = i0; i < 256*192; i += NT) {
    int o = i / 192, k = i - o * 192;
    WAH3[i] = (k < 131) ? f2h_u(W3a[o*262 + k]) : (u16)0;
  }
  for (int i = i0; i < 65536; i += NT) WBH3[i] = f2h_u(W3b[i]);
}

// ---------------- conv_a VALU GEMM: MODE 0 = T-pass; MODE 1 = L1 edge stats-only ----------------
template<int C2, int CM, int MODE>
__global__ __launch_bounds__(256) void conv_a_gemm(
    const float* __restrict__ F, size_t fbstride,
    const int* __restrict__ idx,
    const float* __restrict__ Wt,
    const float* __restrict__ bias,
    const float* __restrict__ T,
    float* __restrict__ Tout,
    float* __restrict__ red_s, float* __restrict__ red_q,
    int M)
{
  constexpr int KP = (C2 + 3) & ~3;
  constexpr int KC = (KP <= 68) ? KP : 44;
  __shared__ float At[64][KC];
  __shared__ float Wts[KC][64];
  __shared__ int ji[64];
  __shared__ float sred[4][64];
  __shared__ float qred[4][64];
  const int t = threadIdx.x;
  const int rt = blockIdx.x, ot = blockIdx.y, b = blockIdx.z;
  const int R0 = rt * 64, oc0 = ot * 64;
  const float* Fb = F + (size_t)b * fbstride;

  if (t < 64) {
    int gr = R0 + t;
    ji[t] = (MODE == 0) ? gr : idx[((size_t)b * M + (gr >> 5)) * KNN + (gr & 31)];
  }

  const int cg = t & 15, rg = t >> 4;
  const int r0 = rg * 4, c0 = cg * 4;
  float acc[4][4];
  if (MODE == 0) {
#pragma unroll
    for (int j = 0; j < 4; ++j) {
      float bv = bias[oc0 + c0 + j];
#pragma unroll
      for (int i = 0; i < 4; ++i) acc[i][j] = bv;
    }
  } else {
#pragma unroll
    for (int i = 0; i < 4; ++i) {
      const float* tp = T + ((size_t)b * M + (size_t)((R0 + r0 + i) >> 5)) * CM + oc0 + c0;
      acc[i][0] = tp[0]; acc[i][1] = tp[1]; acc[i][2] = tp[2]; acc[i][3] = tp[3];
    }
  }
  __syncthreads();

  for (int k0 = 0; k0 < KP; k0 += KC) {
    if (k0) __syncthreads();
    for (int i = t; i < KC * 64; i += 256) {
      int c = i >> 6, o = i & 63;
      Wts[c][o] = Wt[(size_t)(k0 + c) * CM + oc0 + o];
    }
    if constexpr (C2 == 3) {
      for (int i = t; i < 64 * 4; i += 256) {
        int r = i >> 2, c = i & 3;
        At[r][c] = (c < 3) ? Fb[(size_t)ji[r] * 3 + c] : 0.f;
      }
    } else {
      constexpr int C4 = KC / 4;
      for (int i = t; i < 64 * C4; i += 256) {
        int r = i / C4, c4 = i - r * C4;
        *(float4*)&At[r][c4 * 4] = *(const float4*)&Fb[(size_t)ji[r] * KP + k0 + c4 * 4];
      }
    }
    __syncthreads();

#pragma unroll 4
    for (int k = 0; k < KC; ++k) {
      const float4 w4 = *(const float4*)&Wts[k][c0];
      float a0 = At[r0][k], a1 = At[r0+1][k], a2 = At[r0+2][k], a3 = At[r0+3][k];
      acc[0][0]=fmaf(a0,w4.x,acc[0][0]); acc[0][1]=fmaf(a0,w4.y,acc[0][1]);
      acc[0][2]=fmaf(a0,w4.z,acc[0][2]); acc[0][3]=fmaf(a0,w4.w,acc[0][3]);
      acc[1][0]=fmaf(a1,w4.x,acc[1][0]); acc[1][1]=fmaf(a1,w4.y,acc[1][1]);
      acc[1][2]=fmaf(a1,w4.z,acc[1][2]); acc[1][3]=fmaf(a1,w4.w,acc[1][3]);
      acc[2][0]=fmaf(a2,w4.x,acc[2][0]); acc[2][1]=fmaf(a2,w4.y,acc[2][1]);
      acc[2][2]=fmaf(a2,w4.z,acc[2][2]); acc[2][3]=fmaf(a2,w4.w,acc[2][3]);
      acc[3][0]=fmaf(a3,w4.x,acc[3][0]); acc[3][1]=fmaf(a3,w4.y,acc[3][1]);
      acc[3][2]=fmaf(a3,w4.z,acc[3][2]); acc[3][3]=fmaf(a3,w4.w,acc[3][3]);
    }
  }

  if (MODE == 0) {
    float* op = Tout + ((size_t)b * M + R0) * (size_t)CM + oc0;
#pragma unroll
    for (int i = 0; i < 4; ++i) {
      float* p = op + (size_t)(r0 + i) * CM + c0;
      p[0]=acc[i][0]; p[1]=acc[i][1]; p[2]=acc[i][2]; p[3]=acc[i][3];
    }
  } else {
    float cs[4], cq_[4];
#pragma unroll
    for (int j = 0; j < 4; ++j) {
      float s = acc[0][j] + acc[1][j] + acc[2][j] + acc[3][j];
      float q = acc[0][j]*acc[0][j] + acc[1][j]*acc[1][j] + acc[2][j]*acc[2][j] + acc[3][j]*acc[3][j];
      s += __shfl_xor(s, 16); q += __shfl_xor(q, 16);
      s += __shfl_xor(s, 32); q += __shfl_xor(q, 32);
      cs[j] = s; cq_[j] = q;
    }
    const int wv = t >> 6;
    if ((t & 48) == 0) {
#pragma unroll
      for (int j = 0; j < 4; ++j) { sred[wv][c0 + j] = cs[j]; qred[wv][c0 + j] = cq_[j]; }
    }
    __syncthreads();
    if (t < 64) {
      float s = sred[0][t] + sred[1][t] + sred[2][t] + sred[3][t];
      float q = qred[0][t] + qred[1][t] + qred[2][t] + qred[3][t];
      int shdw = (rt & 15) * 256;
      atomicAdd(&red_s[shdw + t], s);
      atomicAdd(&red_q[shdw + t], q);
    }
  }
}

// ---------------- l1_convb: recompute h1 from xyz, bn1(inline finalize)+relu, MFMA, stats2+max ----------------
__global__ __launch_bounds__(256) void l1_convb(
    const float* __restrict__ pcd,
    const int* __restrict__ idx,
    const float* __restrict__ WAT,
    const float* __restrict__ T,
    const u16* __restrict__ Wbh,
    const float* __restrict__ bb,
    const float* __restrict__ gA, const float* __restrict__ beA,
    const float* __restrict__ redA_s, const float* __restrict__ redA_q,
    float* __restrict__ redB_s, float* __restrict__ redB_q,
    float* __restrict__ hmax)
{
  __shared__ u16 Alds[64][72];
  __shared__ u16 Wlds[64][72];
  __shared__ float xyzs[64][4];
  __shared__ float was[3][64];
  __shared__ float scs[64], shs[64];
  __shared__ int ji[64];
  const int t = threadIdx.x;
  const int lane = t & 63, w = t >> 6;
  const int wr = w >> 1, wc = w & 1;
  const int cl = lane & 15, rq = lane >> 4;
  const int rt = blockIdx.x, b = blockIdx.y;
  const int R0 = rt * 64;
  const float* pb = pcd + (size_t)b * 12288;

  if (t < 64) ji[t] = idx[((size_t)b * 4096 + ((R0 + t) >> 5)) * KNN + ((R0 + t) & 31)];
  if (t < 192) was[t / 64][t & 63] = WAT[t];
  if (t >= 192) bn_from_red(t - 192, redA_s, redA_q, gA, beA, 1.f/1048576.f, scs, shs);
  for (int i = t; i < 64 * 8; i += 256) {
    int o = i >> 3, seg = i & 7;
    *(float4*)&Wlds[o][seg * 8] = *(const float4*)&Wbh[(size_t)o * 64 + seg * 8];
  }
  __syncthreads();
  if (t < 64) {
    const float* p = pb + (size_t)ji[t] * 3;
    xyzs[t][0] = p[0]; xyzs[t][1] = p[1]; xyzs[t][2] = p[2]; xyzs[t][3] = 0.f;
  }
  __syncthreads();

  for (int i = t; i < 64 * 8; i += 256) {
    int r = i >> 3, seg = i & 7;
    float px = xyzs[r][0], py = xyzs[r][1], pz = xyzs[r][2];
    const float* Tm = T + ((size_t)b * 4096 + (size_t)((R0 + r) >> 5)) * 64;
    half8 ov;
#pragma unroll
    for (int j2 = 0; j2 < 8; ++j2) {
      int c = seg * 8 + j2;
      float hh = Tm[c];
      hh = fmaf(px, was[0][c], hh);
      hh = fmaf(py, was[1][c], hh);
      hh = fmaf(pz, was[2][c], hh);
      ov[j2] = (_Float16)fmaxf(0.f, fmaf(hh, scs[c], shs[c]));
    }
    *(half8*)&Alds[r][seg * 8] = ov;
  }
  __syncthreads();

  f32x4 acc[2][2];
#pragma unroll
  for (int fr = 0; fr < 2; ++fr)
#pragma unroll
    for (int fc = 0; fc < 2; ++fc) {
      float bv = bb[wc * 32 + fc * 16 + cl];
#pragma unroll
      for (int r = 0; r < 4; ++r) acc[fr][fc][r] = bv;
    }

#pragma unroll
  for (int kk = 0; kk < 2; ++kk) {
    half8 af[2], bf[2];
#pragma unroll
    for (int fr = 0; fr < 2; ++fr)
      af[fr] = *(const half8*)&Alds[wr*32 + fr*16 + cl][kk*32 + rq*8];
#pragma unroll
    for (int fc = 0; fc < 2; ++fc)
      bf[fc] = *(const half8*)&Wlds[wc*32 + fc*16 + cl][kk*32 + rq*8];
#pragma unroll
    for (int fr = 0; fr < 2; ++fr)
#pragma unroll
      for (int fc = 0; fc < 2; ++fc)
        acc[fr][fc] = __builtin_amdgcn_mfma_f32_16x16x32_f16(af[fr], bf[fc], acc[fr][fc], 0, 0, 0);
  }

#pragma unroll
  for (int fc = 0; fc < 2; ++fc) {
    float s = 0.f, q = 0.f, mx = -3.4e38f;
#pragma unroll
    for (int fr = 0; fr < 2; ++fr)
#pragma unroll
      for (int r = 0; r < 4; ++r) {
        float v = acc[fr][fc][r];
        s += v; q += v * v; mx = fmaxf(mx, v);
      }
    s += __shfl_xor(s, 16); q += __shfl_xor(q, 16); mx = fmaxf(mx, __shfl_xor(mx, 16));
    s += __shfl_xor(s, 32); q += __shfl_xor(q, 32); mx = fmaxf(mx, __shfl_xor(mx, 32));
    if (rq == 0) {
      int col = wc * 32 + fc * 16 + cl;
      int shdw = (rt & 15) * 256;
      atomicAdd(&redB_s[shdw + col], s);
      atomicAdd(&redB_q[shdw + col], q);
      hmax[((size_t)b * 4096 + (size_t)(rt * 2 + wr)) * 64 + col] = mx;
    }
  }
}

// ---------------- conv_a MFMA (L2/L3 edge) + fused bn1 stats; H stored fp8 ----------------
template<int CM, int KPAD>
__global__ __launch_bounds__(256) void conv_a_mfma(
    const float* __restrict__ F, int fstride, size_t fbstride,
    const int* __restrict__ idx, int idxstride,
    const u16* __restrict__ Wh,
    const float* __restrict__ T,
    u32* __restrict__ H32,
    float* __restrict__ red_s, float* __restrict__ red_q,
    int M)
{
  constexpr int FC = CM / 32;
  __shared__ u16 Alds[64][72];
  __shared__ u16 Wlds[CM][72];
  __shared__ int ji[64];
  const int t = threadIdx.x;
  const int lane = t & 63, w = t >> 6;
  const int wr = w >> 1, wc = w & 1;
  const int cl = lane & 15, rq = lane >> 4;
  const int rt = blockIdx.x, b = blockIdx.y;
  const int R0 = rt * 64;
  const float* Fb = F + (size_t)b * fbstride;

  if (t < 64) ji[t] = idx[((size_t)b * idxstride + ((R0 + t) >> 5)) * KNN + ((R0 + t) & 31)];

  f32x4 acc[2][FC];
#pragma unroll
  for (int fr = 0; fr < 2; ++fr)
#pragma unroll
    for (int fc = 0; fc < FC; ++fc) {
      int col = wc * (CM/2) + fc * 16 + cl;
#pragma unroll
      for (int r = 0; r < 4; ++r) {
        int row = R0 + wr*32 + fr*16 + rq*4 + r;
        acc[fr][fc][r] = T[((size_t)b * M + (row >> 5)) * CM + col];
      }
    }
  __syncthreads();

  for (int k0 = 0; k0 < KPAD; k0 += 64) {
    if (k0) __syncthreads();
    for (int i = t; i < 64 * 16; i += 256) {
      int r = i >> 4, seg = i & 15;
      int k = k0 + seg * 4;
      ushort4 s = {0,0,0,0};
      if (k < fstride) {
        float4 v = *(const float4*)&Fb[(size_t)ji[r] * fstride + k];
        s.x = f2h_u(v.x); s.y = f2h_u(v.y); s.z = f2h_u(v.z); s.w = f2h_u(v.w);
      }
      *(ushort4*)&Alds[r][seg * 4] = s;
    }
    for (int i = t; i < CM * 8; i += 256) {
      int o = i >> 3, seg = i & 7;
      *(float4*)&Wlds[o][seg * 8] = *(const float4*)&Wh[(size_t)o * KPAD + k0 + seg * 8];
    }
    __syncthreads();

#pragma unroll
    for (int kk = 0; kk < 2; ++kk) {
      half8 af[2], bf[FC];
#pragma unroll
      for (int fr = 0; fr < 2; ++fr)
        af[fr] = *(const half8*)&Alds[wr*32 + fr*16 + cl][kk*32 + rq*8];
#pragma unroll
      for (int fc = 0; fc < FC; ++fc)
        bf[fc] = *(const half8*)&Wlds[wc*(CM/2) + fc*16 + cl][kk*32 + rq*8];
#pragma unroll
      for (int fr = 0; fr < 2; ++fr)
#pragma unroll
        for (int fc = 0; fc < FC; ++fc)
          acc[fr][fc] = __builtin_amdgcn_mfma_f32_16x16x32_f16(af[fr], bf[fc], acc[fr][fc], 0, 0, 0);
    }
  }

  u32* Hb4 = H32 + ((size_t)b * ((size_t)M * KNN / 4) + (size_t)(R0 >> 2)) * CM;
#pragma unroll
  for (int fr = 0; fr < 2; ++fr)
#pragma unroll
    for (int fc = 0; fc < FC; ++fc) {
      int col = wc*(CM/2) + fc*16 + cl;
      u32 v = __builtin_amdgcn_cvt_pk_fp8_f32(acc[fr][fc][0], acc[fr][fc][1], 0, false);
      v = __builtin_amdgcn_cvt_pk_fp8_f32(acc[fr][fc][2], acc[fr][fc][3], v, true);
      Hb4[(size_t)(wr*8 + fr*4 + rq) * CM + col] = v;
    }

#pragma unroll
  for (int fc = 0; fc < FC; ++fc) {
    float s = 0.f, q = 0.f;
#pragma unroll
    for (int fr = 0; fr < 2; ++fr)
#pragma unroll
      for (int r = 0; r < 4; ++r) {
        float v = acc[fr][fc][r];
        s += v; q += v * v;
      }
    s += __shfl_xor(s, 16); q += __shfl_xor(q, 16);
    s += __shfl_xor(s, 32); q += __shfl_xor(q, 32);
    if (rq == 0) {
      int col = wc*(CM/2) + fc*16 + cl;
      int shdw = (rt & 15) * 256;
      atomicAdd(&red_s[shdw + col], s);
      atomicAdd(&red_q[shdw + col], q);
    }
  }
}

// ---------------- conv_b MFMA fused: 128 rows/block, inline bn1 finalize, stats2 + max ----------------
template<int CM>
__global__ __launch_bounds__(512) void conv_b_fused(
    const u32* __restrict__ H32,
    const u16* __restrict__ Wh,
    const float* __restrict__ bb,
    const float* __restrict__ gA, const float* __restrict__ beA,
    const float* __restrict__ redA_s, const float* __restrict__ redA_q, float invcnt,
    float* __restrict__ redB_s, float* __restrict__ redB_q,
    float* __restrict__ hmax,
    int Mrows)
{
  constexpr int FC = CM / 32;
  __shared__ u16 Alds[128][72];
  __shared__ u16 Wlds[CM][72];
  __shared__ float scs[CM], shs[CM];
  const int t = threadIdx.x;
  const int lane = t & 63, w = t >> 6;
  const int wr = w >> 1;
  const int wc = w & 1;
  const int cl = lane & 15, rq = lane >> 4;
  const int rt = blockIdx.x, b = blockIdx.y;
  const u32* Hb4 = H32 + ((size_t)b * ((size_t)Mrows / 4) + (size_t)(rt * 32)) * CM;

  for (int i = t; i < CM; i += 512) bn_from_red(i, redA_s, redA_q, gA, beA, invcnt, scs, shs);

  f32x4 acc[2][FC];
#pragma unroll
  for (int fr = 0; fr < 2; ++fr)
#pragma unroll
    for (int fc = 0; fc < FC; ++fc) {
      float bv = bb[wc * (CM/2) + fc * 16 + cl];
#pragma unroll
      for (int r = 0; r < 4; ++r) acc[fr][fc][r] = bv;
    }
  __syncthreads();

  for (int k0 = 0; k0 < CM; k0 += 64) {
    if (k0) __syncthreads();
    for (int i = t; i < 128 * 8; i += 512) {
      int r = i >> 3, seg = i & 7;
      int rg = r >> 2, sh8 = (r & 3) * 8;
      const u32* hp = Hb4 + (size_t)rg * CM + k0 + seg * 8;
      half8 ov;
#pragma unroll
      for (int j = 0; j < 8; ++j) {
        float v = __builtin_amdgcn_cvt_f32_fp8((hp[j] >> sh8) & 0xffu, 0);
        int c = k0 + seg * 8 + j;
        v = fmaxf(0.f, fmaf(v, scs[c], shs[c]));
        ov[j] = (_Float16)v;
      }
      *(half8*)&Alds[r][seg * 8] = ov;
    }
    for (int i = t; i < CM * 8; i += 512) {
      int o = i >> 3, seg = i & 7;
      *(float4*)&Wlds[o][seg * 8] = *(const float4*)&Wh[(size_t)o * CM + k0 + seg * 8];
    }
    __syncthreads();

#pragma unroll
    for (int kk = 0; kk < 2; ++kk) {
      half8 af[2], bf[FC];
#pragma unroll
      for (int fr = 0; fr < 2; ++fr)
        af[fr] = *(const half8*)&Alds[wr*32 + fr*16 + cl][kk*32 + rq*8];
#pragma unroll
      for (int fc = 0; fc < FC; ++fc)
        bf[fc] = *(const half8*)&Wlds[wc*(CM/2) + fc*16 + cl][kk*32 + rq*8];
#pragma unroll
      for (int fr = 0; fr < 2; ++fr)
#pragma unroll
        for (int fc = 0; fc < FC; ++fc)
          acc[fr][fc] = __builtin_amdgcn_mfma_f32_16x16x32_f16(af[fr], bf[fc], acc[fr][fc], 0, 0, 0);
    }
  }

#pragma unroll
  for (int fc = 0; fc < FC; ++fc) {
    float s = 0.f, q = 0.f, mx = -3.4e38f;
#pragma unroll
    for (int fr = 0; fr < 2; ++fr)
#pragma unroll
      for (int r = 0; r < 4; ++r) {
        float v = acc[fr][fc][r];
        s += v; q += v * v; mx = fmaxf(mx, v);
      }
    s += __shfl_xor(s, 16); q += __shfl_xor(q, 16); mx = fmaxf(mx, __shfl_xor(mx, 16));
    s += __shfl_xor(s, 32); q += __shfl_xor(q, 32); mx = fmaxf(mx, __shfl_xor(mx, 32));
    if (rq == 0) {
      int col = wc*(CM/2) + fc*16 + cl;
      int shdw = (rt & 15) * 256;
      atomicAdd(&redB_s[shdw + col], s);
      atomicAdd(&redB_q[shdw + col], q);
      hmax[((size_t)b * (Mrows >> 5) + (size_t)(rt * 4 + wr)) * CM + col] = mx;
    }
  }
}

// ---------------- bn2(inline finalize) + relu on max values -> feature buffer (+ xyz append) ----------------
__global__ __launch_bounds__(256) void bnrelu_fb(const float* __restrict__ hm,
    const float* __restrict__ gB, const float* __restrict__ beB,
    const float* __restrict__ redB_s, const float* __restrict__ redB_q, float invcnt,
    const float* __restrict__ pcd,
    float* __restrict__ fout, int CM, int fostride, size_t fobstride, int M) {
  __shared__ float scs[256], shs[256];
  for (int o = threadIdx.x; o < CM; o += 256) bn_from_red(o, redB_s, redB_q, gB, beB, invcnt, scs, shs);
  __syncthreads();
  int i = blockIdx.x * 256 + threadIdx.x;
  int cq = CM >> 2;
  int total = B8 * M * cq;
  if (i >= total) return;
  int c4 = i % cq; int r = i / cq;
  int b = r / M, m = r - b * M;
  float4 v = *(const float4*)&hm[((size_t)b * M + m) * CM + c4 * 4];
  int c = c4 * 4;
  float4 o;
  o.x = fmaxf(0.f, fmaf(v.x, scs[c],   shs[c]));
  o.y = fmaxf(0.f, fmaf(v.y, scs[c+1], shs[c+1]));
  o.z = fmaxf(0.f, fmaf(v.z, scs[c+2], shs[c+2]));
  o.w = fmaxf(0.f, fmaf(v.w, scs[c+3], shs[c+3]));
  float* op = fout + (size_t)b * fobstride + (size_t)m * fostride;
  *(float4*)(op + c) = o;
  if (pcd && c4 == 0) {
    const float* p = pcd + ((size_t)b * 4096 + m) * 3;
    *(float4*)(op + CM) = make_float4(p[0], p[1], p[2], 0.f);
  }
}

// ---------------- final FC + feat transpose ----------------
__global__ __launch_bounds__(256) void fc_out(const float* __restrict__ f4,
                                              const float* __restrict__ fcW, const float* __restrict__ fcb,
                                              float* __restrict__ out1, float* __restrict__ out3) {
  __shared__ float tile[32 * 257];
  const int t = threadIdx.x, b = blockIdx.x, n0 = blockIdx.y * 32;
  for (int i = t; i < 32 * 256; i += 256) {
    int n = i >> 8, c = i & 255;
    tile[n * 257 + c] = f4[((size_t)b * 1024 + n0 + n) * 256 + c];
  }
  __syncthreads();
  const int n = t & 31, og = t >> 5;
#pragma unroll
  for (int ci = 0; ci < 32; ++ci) {
    int c = og * 32 + ci;
    out3[((size_t)b * 256 + c) * 1024 + n0 + n] = tile[n * 257 + c];
  }
#pragma unroll
  for (int oi = 0; oi < 16; ++oi) {
    int o = og * 16 + oi;
    float acc = fcb[o];
    const float* w = fcW + (size_t)o * 256;
#pragma unroll 4
    for (int c = 0; c < 256; ++c) acc = fmaf(tile[n * 257 + c], w[c], acc);
    out1[((size_t)b * 128 + o) * 1024 + n0 + n] = acc;
  }
}

__global__ void out_xyz_idx(const float* __restrict__ pcd, float* __restrict__ out0,
                            float* __restrict__ out2) {
  int i = blockIdx.x * 256 + threadIdx.x;
  if (i < B8 * 1024) {
    int b = i >> 10, n = i & 1023;
    const float* p = pcd + ((size_t)b * 4096 + n) * 3;
    float* o = out0 + (size_t)i * 3;
    o[0] = p[0]; o[1] = p[1]; o[2] = p[2];
    out2[i] = (float)n;
  }
}

// ---------------- host ----------------
extern "C" void kernel_launch(void* const* d_in, const int* in_sizes, int n_in,
                              void* d_out, int out_size, void* d_ws, size_t ws_size,
                              hipStream_t stream) {
  (void)in_sizes; (void)n_in; (void)out_size; (void)ws_size;
  const float* pcd = (const float*)d_in[0];
  const float* W1a = (const float*)d_in[1];  const float* b1a = (const float*)d_in[2];
  const float* g1a = (const float*)d_in[3];  const float* be1a= (const float*)d_in[4];
  const float* W1b = (const float*)d_in[5];  const float* b1b = (const float*)d_in[6];
  const float* g1b = (const float*)d_in[7];  const float* be1b= (const float*)d_in[8];
  const float* W2a = (const float*)d_in[9];  const float* b2a = (const float*)d_in[10];
  const float* g2a = (const float*)d_in[11]; const float* be2a= (const float*)d_in[12];
  const float* W2b = (const float*)d_in[13]; const float* b2b = (const float*)d_in[14];
  const float* g2b = (const float*)d_in[15]; const float* be2b= (const float*)d_in[16];
  const float* W3a = (const float*)d_in[17]; const float* b3a = (const float*)d_in[18];
  const float* g3a = (const float*)d_in[19]; const float* be3a= (const float*)d_in[20];
  const float* W3b = (const float*)d_in[21]; const float* b3b = (const float*)d_in[22];
  const float* g3b = (const float*)d_in[23]; const float* be3b= (const float*)d_in[24];
  const float* fcW = (const float*)d_in[25]; const float* fcb = (const float*)d_in[26];

  float* wsf = (float*)d_ws;
  float* FB2 = wsf;                         // 8*4096*68
  float* FB3 = FB2 + 2228224;               // 8*2048*132
  float* FB4 = FB3 + 2162688;               // 8*1024*256
  float* TBUF= FB4 + 2097152;               // 8*4096*64
  float* RED = TBUF + 2097152;              // 6 x 8192
  float* R1A = RED;          float* R1B = RED + 8192;
  float* R2A = RED + 16384;  float* R2B = RED + 24576;
  float* R3A = RED + 32768;  float* R3B = RED + 40960;
  float* WAT1 = RED + 49152;                // 256
  float* WBT1 = WAT1 + 256;                 // 256
  float* WBT2 = WBT1 + 256;                 // 8704
  float* WBT3 = WBT2 + 8704;                // 33792
  float* HMAX = WBT3 + 33792;               // 8*4096*64
  int* IDX1 = (int*)(HMAX + 2097152);       // 8*4096*32
  int* IDX3 = IDX1 + (size_t)8 * 4096 * 32; // 8*1024*32
  u32* H32  = (u32*)(IDX3 + (size_t)8 * 1024 * 32); // 64 MiB fp8 H
  u16* WBH1 = (u16*)(H32 + 16777216);
  u16* WAH2 = WBH1 + 4096;
  u16* WBH2 = WAH2 + 16384;
  u16* WAH3 = WBH2 + 16384;
  u16* WBH3 = WAH3 + 49152;

  float* out0 = (float*)d_out;
  float* out1 = out0 + 24576;
  float* out2 = out1 + 1048576;
  float* out3 = out2 + 8192;

  prep_all<<<64, 256, 0, stream>>>(W1a, W1b, W2a, W2b, W3a, W3b, RED,
                                   WAT1, WBT1, WBH1, WBT2, WAH2, WBH2, WBT3, WAH3, WBH3);

  // ================ Layer 1: C2=3, CM=64, M=4096, N=4096 ================
  knn_kernel<<<dim3(2048, 8), 256, 0, stream>>>(pcd, 4096, 4096, IDX1);
  conv_a_gemm<3,64,0><<<dim3(64,1,8),256,0,stream>>>(pcd,(size_t)12288,nullptr,WBT1,b1a,nullptr,TBUF,nullptr,nullptr,4096);
  conv_a_gemm<3,64,1><<<dim3(2048,1,8),256,0,stream>>>(pcd,(size_t)12288,IDX1,WAT1,nullptr,TBUF,nullptr,R1A,R1A+4096,4096);
  l1_convb<<<dim3(2048,8),256,0,stream>>>(pcd,IDX1,WAT1,TBUF,WBH1,b1b,g1a,be1a,R1A,R1A+4096,R1B,R1B+4096,HMAX);
  bnrelu_fb<<<2048,256,0,stream>>>(HMAX,g1b,be1b,R1B,R1B+4096,1.f/1048576.f,pcd,FB2,64,68,(size_t)278528,4096);

  // ================ Layer 2: C2=67, CM=128, M=2048, N=4096  (IDX2 == IDX1[:, :2048]) ================
  conv_a_gemm<67,128,0><<<dim3(32,2,8),256,0,stream>>>(FB2,(size_t)278528,nullptr,WBT2,b2a,nullptr,TBUF,nullptr,nullptr,2048);
  conv_a_mfma<128,128><<<dim3(1024,8),256,0,stream>>>(FB2,68,(size_t)278528,IDX1,4096,WAH2,TBUF,H32,R2A,R2A+4096,2048);
  conv_b_fused<128><<<dim3(512,8),512,0,stream>>>(H32,WBH2,b2b,g2a,be2a,R2A,R2A+4096,1.f/524288.f,R2B,R2B+4096,HMAX,2048*32);
  bnrelu_fb<<<2048,256,0,stream>>>(HMAX,g2b,be2b,R2B,R2B+4096,1.f/524288.f,pcd,FB3,128,132,(size_t)270336,2048);

  // ================ Layer 3: C2=131, CM=256, M=1024, N=2048 ================
  knn_kernel<<<dim3(512, 8), 256, 0, stream>>>(pcd, 2048, 1024, IDX3);
  conv_a_gemm<131,256,0><<<dim3(16,4,8),256,0,stream>>>(FB3,(size_t)270336,nullptr,WBT3,b3a,nullptr,TBUF,nullptr,nullptr,1024);
  conv_a_mfma<256,192><<<dim3(512,8),256,0,stream>>>(FB3,132,(size_t)270336,IDX3,1024,WAH3,TBUF,H32,R3A,R3A+4096,1024);
  conv_b_fused<256><<<dim3(256,8),512,0,stream>>>(H32,WBH3,b3b,g3a,be3a,R3A,R3A+4096,1.f/262144.f,R3B,R3B+4096,HMAX,1024*32);
  bnrelu_fb<<<2048,256,0,stream>>>(HMAX,g3b,be3b,R3B,R3B+4096,1.f/262144.f,nullptr,FB4,256,256,(size_t)262144,1024);

  // ================ outputs ================
  fc_out<<<dim3(8, 32), 256, 0, stream>>>(FB4, fcW, fcb, out1, out3);
  out_xyz_idx<<<32, 256, 0, stream>>>(pcd, out0, out2);
}

// Round 13
// 753.483 us; speedup vs baseline: 1.1591x; 1.1591x over previous
//
#include <hip/hip_runtime.h>
#include <hip/hip_bf16.h>

#define B8 8
#define KNN 32
typedef unsigned short u16;
typedef unsigned int u32;
typedef unsigned long long u64;

typedef __attribute__((ext_vector_type(8))) _Float16 half8;
typedef __attribute__((ext_vector_type(4))) float f32x4;

static __device__ __forceinline__ u16 f2h_u(float f) {
  _Float16 h = (_Float16)f; u16 u; __builtin_memcpy(&u, &h, 2); return u;
}

// monotonic (distance, id) -> u64 key
static __device__ __forceinline__ u64 enc_key(float d, int id) {
  u32 u = __float_as_uint(d);
  u = (d >= 0.f) ? (u | 0x80000000u) : ~u;
  return ((u64)u << 32) | (u32)id;
}
static __device__ __forceinline__ float dec_val(u64 k) {
  u32 u = (u32)(k >> 32);
  u = (u & 0x80000000u) ? (u & 0x7fffffffu) : ~u;
  return __uint_as_float(u);
}

// rank-redistribute 64 keys (one per lane) -> sorted across lanes; sets tau = 32nd
static __device__ __forceinline__ u64 rank64(u64 mk, int lane, u64* slk, u64* outk, float& tau) {
  slk[lane] = mk;
  int r = 0;
#pragma unroll 16
  for (int j = 0; j < 64; ++j) r += (slk[j] < mk) ? 1 : 0;
  outk[r] = mk;
  u64 res = outk[lane];
  tau = dec_val(outk[31]);
  return res;
}

// per-block BN finalize from 16-shadow sums (bitwise identical to prior bn_finalize)
static __device__ __forceinline__ void bn_from_red(int o, const float* red_s, const float* red_q,
                                                   const float* g, const float* be, float invcnt,
                                                   float* scs, float* shs) {
  float s = 0.f, q = 0.f;
#pragma unroll
  for (int i = 0; i < 16; ++i) { s += red_s[i * 256 + o]; q += red_q[i * 256 + o]; }
  float mu  = s * invcnt;
  float var = fmaxf(q * invcnt - mu * mu, 0.f);
  float scv = g[o] * rsqrtf(var + 1e-5f);
  scs[o] = scv;
  shs[o] = fmaf(-mu, scv, be[o]);
}

// ---------------- KNN: one wave/query (4 waves/block), 1024-pt tiles, rank-sort flush (round-10 winner) ----------------
__global__ __launch_bounds__(256) void knn_kernel(const float* __restrict__ pcd,
                                                  int N, int M, int* __restrict__ idxout) {
  __shared__ float4 pts[1024];
  __shared__ u64 bufk[4][32];
  __shared__ u64 slk[4][64];
  __shared__ u64 outk[4][64];
  const int t = threadIdx.x;
  const int lane = t & 63, w = t >> 6;
  const int b = blockIdx.y;
  const int m = blockIdx.x * 4 + w;
  const float* base = pcd + (size_t)b * 12288;
  const float qx = base[m*3], qy = base[m*3+1], qz = base[m*3+2];
  const float ax = -2.f*qx, ay = -2.f*qy, az = -2.f*qz;

  u64 heldk; float tau; int cnt = 0;

  for (int i = t; i < 1024; i += 256) {
    const float* p = base + (size_t)i * 3;
    float x = p[0], y = p[1], z = p[2];
    pts[i] = make_float4(x, y, z, x*x + y*y + z*z);
  }
  __syncthreads();

  // init: rank-sort first 64 candidates
  {
    float4 p = pts[lane];
    float r0 = fmaf(ax, p.x, fmaf(ay, p.y, fmaf(az, p.z, p.w)));
    heldk = rank64(enc_key(r0, lane), lane, slk[w], outk[w], tau);
  }

  for (int n0 = 0; n0 < N; n0 += 1024) {
    if (n0) {
      __syncthreads();
      for (int i = t; i < 1024; i += 256) {
        const float* p = base + (size_t)(n0 + i) * 3;
        float x = p[0], y = p[1], z = p[2];
        pts[i] = make_float4(x, y, z, x*x + y*y + z*z);
      }
      __syncthreads();
    }
    for (int c = 0; c < 1024; c += 256) {
      float4 p0 = pts[c + lane];
      float4 p1 = pts[c + 64 + lane];
      float4 p2 = pts[c + 128 + lane];
      float4 p3 = pts[c + 192 + lane];
      float r[4];
      r[0] = fmaf(ax, p0.x, fmaf(ay, p0.y, fmaf(az, p0.z, p0.w)));
      r[1] = fmaf(ax, p1.x, fmaf(ay, p1.y, fmaf(az, p1.z, p1.w)));
      r[2] = fmaf(ax, p2.x, fmaf(ay, p2.y, fmaf(az, p2.z, p2.w)));
      r[3] = fmaf(ax, p3.x, fmaf(ay, p3.y, fmaf(az, p3.z, p3.w)));
      if (n0 == 0 && c == 0) r[0] = 3.4e38f;   // first 64 consumed by init
      float rmn = fminf(fminf(r[0], r[1]), fminf(r[2], r[3]));
      if (!__any(rmn < tau)) continue;
#pragma unroll
      for (int j = 0; j < 4; ++j) {
        float rr = r[j];
        if (!__any(rr < tau)) continue;
        int gid = n0 + c + j * 64 + lane;
        bool pass = rr < tau;
        while (__any(pass)) {
          u64 mk_ = __ballot(pass);
          int before = __popcll(mk_ & ((1ull << lane) - 1ull));
          int total  = __popcll(mk_);
          int room = 32 - cnt;
          if (pass && before < room) {
            bufk[w][cnt + before] = enc_key(rr, gid);
            pass = false;
          }
          if (total >= room) {
            u64 mk = (lane < 32) ? heldk : bufk[w][lane - 32];
            heldk = rank64(mk, lane, slk[w], outk[w], tau);
            cnt = 0;
            pass = pass && (rr < tau);
          } else {
            cnt += total;
          }
        }
      }
    }
  }
  if (cnt > 0) {
    int bl = lane - 32;
    u64 mk = (lane < 32) ? heldk
             : ((bl < cnt) ? bufk[w][bl]
                           : ((0xFFFFFFFFull << 32) | (0xFFFFFF00u | (u32)lane)));
    heldk = rank64(mk, lane, slk[w], outk[w], tau);
  }
  if (lane < KNN) idxout[((size_t)b * M + m) * KNN + lane] = (int)(u32)(heldk & 0xFFFFFFFFu);
}

// ---------------- prep_all ----------------
__global__ void prep_all(
    const float* __restrict__ W1a, const float* __restrict__ W1b,
    const float* __restrict__ W2a, const float* __restrict__ W2b,
    const float* __restrict__ W3a, const float* __restrict__ W3b,
    float* __restrict__ RED,
    float* __restrict__ WAT1, float* __restrict__ WBT1, u16* __restrict__ WBH1,
    float* __restrict__ WBT2, u16* __restrict__ WAH2, u16* __restrict__ WBH2,
    float* __restrict__ WBT3, u16* __restrict__ WAH3, u16* __restrict__ WBH3)
{
  int i0 = blockIdx.x * 256 + threadIdx.x;
  int NT = gridDim.x * 256;
  for (int i = i0; i < 49152; i += NT) RED[i] = 0.f;     // 6 RED buffers
  for (int i = i0; i < 256; i += NT) {
    int c = i >> 6, o = i & 63;
    float w1 = (c < 3) ? W1a[o*6 + c] : 0.f;
    float w2 = (c < 3) ? W1a[o*6 + 3 + c] : 0.f;
    WAT1[i] = w1; WBT1[i] = w2 - w1;
  }
  for (int i = i0; i < 4096; i += NT) WBH1[i] = f2h_u(W1b[i]);
  for (int i = i0; i < 68*128; i += NT) {
    int c = i >> 7, o = i & 127;
    float w1 = 0.f, w2 = 0.f;
    if (c < 67) { w1 = W2a[o*134 + c]; w2 = W2a[o*134 + 67 + c]; }
    WBT2[i] = w2 - w1;
  }
  for (int i = i0; i < 128*128; i += NT) {
    int o = i >> 7, k = i & 127;
    WAH2[i] = (k < 67) ? f2h_u(W2a[o*134 + k]) : (u16)0;
  }
  for (int i = i0; i < 16384; i += NT) WBH2[i] = f2h_u(W2b[i]);
  for (int i = i0; i < 132*256; i += NT) {
    int c = i >> 8, o = i & 255;
    float w1 = 0.f, w2 = 0.f;
    if (c < 131) { w1 = W3a[o*262 + c]; w2 = W3a[o*262 + 131 + c]; }
    WBT3[i] = w2 - w1;
  }
  for (int i = i0; i < 256*192; i += NT) {
    int o = i / 192, k = i - o * 192;
    WAH3[i] = (k < 131) ? f2h_u(W3a[o*262 + k]) : (u16)0;
  }
  for (int i = i0; i < 65536; i += NT) WBH3[i] = f2h_u(W3b[i]);
}

// ---------------- conv_a VALU GEMM: MODE 0 = T-pass; MODE 1 = L1 edge stats-only ----------------
template<int C2, int CM, int MODE>
__global__ __launch_bounds__(256) void conv_a_gemm(
    const float* __restrict__ F, size_t fbstride,
    const int* __restrict__ idx,
    const float* __restrict__ Wt,
    const float* __restrict__ bias,
    const float* __restrict__ T,
    float* __restrict__ Tout,
    float* __restrict__ red_s, float* __restrict__ red_q,
    int M)
{
  constexpr int KP = (C2 + 3) & ~3;
  constexpr int KC = (KP <= 68) ? KP : 44;
  __shared__ float At[64][KC];
  __shared__ float Wts[KC][64];
  __shared__ int ji[64];
  __shared__ float sred[4][64];
  __shared__ float qred[4][64];
  const int t = threadIdx.x;
  const int rt = blockIdx.x, ot = blockIdx.y, b = blockIdx.z;
  const int R0 = rt * 64, oc0 = ot * 64;
  const float* Fb = F + (size_t)b * fbstride;

  if (t < 64) {
    int gr = R0 + t;
    ji[t] = (MODE == 0) ? gr : idx[((size_t)b * M + (gr >> 5)) * KNN + (gr & 31)];
  }

  const int cg = t & 15, rg = t >> 4;
  const int r0 = rg * 4, c0 = cg * 4;
  float acc[4][4];
  if (MODE == 0) {
#pragma unroll
    for (int j = 0; j < 4; ++j) {
      float bv = bias[oc0 + c0 + j];
#pragma unroll
      for (int i = 0; i < 4; ++i) acc[i][j] = bv;
    }
  } else {
#pragma unroll
    for (int i = 0; i < 4; ++i) {
      const float* tp = T + ((size_t)b * M + (size_t)((R0 + r0 + i) >> 5)) * CM + oc0 + c0;
      acc[i][0] = tp[0]; acc[i][1] = tp[1]; acc[i][2] = tp[2]; acc[i][3] = tp[3];
    }
  }
  __syncthreads();

  for (int k0 = 0; k0 < KP; k0 += KC) {
    if (k0) __syncthreads();
    for (int i = t; i < KC * 64; i += 256) {
      int c = i >> 6, o = i & 63;
      Wts[c][o] = Wt[(size_t)(k0 + c) * CM + oc0 + o];
    }
    if constexpr (C2 == 3) {
      for (int i = t; i < 64 * 4; i += 256) {
        int r = i >> 2, c = i & 3;
        At[r][c] = (c < 3) ? Fb[(size_t)ji[r] * 3 + c] : 0.f;
      }
    } else {
      constexpr int C4 = KC / 4;
      for (int i = t; i < 64 * C4; i += 256) {
        int r = i / C4, c4 = i - r * C4;
        *(float4*)&At[r][c4 * 4] = *(const float4*)&Fb[(size_t)ji[r] * KP + k0 + c4 * 4];
      }
    }
    __syncthreads();

#pragma unroll 4
    for (int k = 0; k < KC; ++k) {
      const float4 w4 = *(const float4*)&Wts[k][c0];
      float a0 = At[r0][k], a1 = At[r0+1][k], a2 = At[r0+2][k], a3 = At[r0+3][k];
      acc[0][0]=fmaf(a0,w4.x,acc[0][0]); acc[0][1]=fmaf(a0,w4.y,acc[0][1]);
      acc[0][2]=fmaf(a0,w4.z,acc[0][2]); acc[0][3]=fmaf(a0,w4.w,acc[0][3]);
      acc[1][0]=fmaf(a1,w4.x,acc[1][0]); acc[1][1]=fmaf(a1,w4.y,acc[1][1]);
      acc[1][2]=fmaf(a1,w4.z,acc[1][2]); acc[1][3]=fmaf(a1,w4.w,acc[1][3]);
      acc[2][0]=fmaf(a2,w4.x,acc[2][0]); acc[2][1]=fmaf(a2,w4.y,acc[2][1]);
      acc[2][2]=fmaf(a2,w4.z,acc[2][2]); acc[2][3]=fmaf(a2,w4.w,acc[2][3]);
      acc[3][0]=fmaf(a3,w4.x,acc[3][0]); acc[3][1]=fmaf(a3,w4.y,acc[3][1]);
      acc[3][2]=fmaf(a3,w4.z,acc[3][2]); acc[3][3]=fmaf(a3,w4.w,acc[3][3]);
    }
  }

  if (MODE == 0) {
    float* op = Tout + ((size_t)b * M + R0) * (size_t)CM + oc0;
#pragma unroll
    for (int i = 0; i < 4; ++i) {
      float* p = op + (size_t)(r0 + i) * CM + c0;
      p[0]=acc[i][0]; p[1]=acc[i][1]; p[2]=acc[i][2]; p[3]=acc[i][3];
    }
  } else {
    float cs[4], cq_[4];
#pragma unroll
    for (int j = 0; j < 4; ++j) {
      float s = acc[0][j] + acc[1][j] + acc[2][j] + acc[3][j];
      float q = acc[0][j]*acc[0][j] + acc[1][j]*acc[1][j] + acc[2][j]*acc[2][j] + acc[3][j]*acc[3][j];
      s += __shfl_xor(s, 16); q += __shfl_xor(q, 16);
      s += __shfl_xor(s, 32); q += __shfl_xor(q, 32);
      cs[j] = s; cq_[j] = q;
    }
    const int wv = t >> 6;
    if ((t & 48) == 0) {
#pragma unroll
      for (int j = 0; j < 4; ++j) { sred[wv][c0 + j] = cs[j]; qred[wv][c0 + j] = cq_[j]; }
    }
    __syncthreads();
    if (t < 64) {
      float s = sred[0][t] + sred[1][t] + sred[2][t] + sred[3][t];
      float q = qred[0][t] + qred[1][t] + qred[2][t] + qred[3][t];
      int shdw = (rt & 15) * 256;
      atomicAdd(&red_s[shdw + t], s);
      atomicAdd(&red_q[shdw + t], q);
    }
  }
}

// ---------------- l1_convb: recompute h1 from xyz, bn1(inline finalize)+relu, MFMA, stats2+max ----------------
__global__ __launch_bounds__(256) void l1_convb(
    const float* __restrict__ pcd,
    const int* __restrict__ idx,
    const float* __restrict__ WAT,
    const float* __restrict__ T,
    const u16* __restrict__ Wbh,
    const float* __restrict__ bb,
    const float* __restrict__ gA, const float* __restrict__ beA,
    const float* __restrict__ redA_s, const float* __restrict__ redA_q,
    float* __restrict__ redB_s, float* __restrict__ redB_q,
    float* __restrict__ hmax)
{
  __shared__ u16 Alds[64][72];
  __shared__ u16 Wlds[64][72];
  __shared__ float xyzs[64][4];
  __shared__ float was[3][64];
  __shared__ float scs[64], shs[64];
  __shared__ int ji[64];
  const int t = threadIdx.x;
  const int lane = t & 63, w = t >> 6;
  const int wr = w >> 1, wc = w & 1;
  const int cl = lane & 15, rq = lane >> 4;
  const int rt = blockIdx.x, b = blockIdx.y;
  const int R0 = rt * 64;
  const float* pb = pcd + (size_t)b * 12288;

  if (t < 64) ji[t] = idx[((size_t)b * 4096 + ((R0 + t) >> 5)) * KNN + ((R0 + t) & 31)];
  if (t < 192) was[t / 64][t & 63] = WAT[t];
  if (t >= 192) bn_from_red(t - 192, redA_s, redA_q, gA, beA, 1.f/1048576.f, scs, shs);
  for (int i = t; i < 64 * 8; i += 256) {
    int o = i >> 3, seg = i & 7;
    *(float4*)&Wlds[o][seg * 8] = *(const float4*)&Wbh[(size_t)o * 64 + seg * 8];
  }
  __syncthreads();
  if (t < 64) {
    const float* p = pb + (size_t)ji[t] * 3;
    xyzs[t][0] = p[0]; xyzs[t][1] = p[1]; xyzs[t][2] = p[2]; xyzs[t][3] = 0.f;
  }
  __syncthreads();

  for (int i = t; i < 64 * 8; i += 256) {
    int r = i >> 3, seg = i & 7;
    float px = xyzs[r][0], py = xyzs[r][1], pz = xyzs[r][2];
    const float* Tm = T + ((size_t)b * 4096 + (size_t)((R0 + r) >> 5)) * 64;
    half8 ov;
#pragma unroll
    for (int j2 = 0; j2 < 8; ++j2) {
      int c = seg * 8 + j2;
      float hh = Tm[c];
      hh = fmaf(px, was[0][c], hh);
      hh = fmaf(py, was[1][c], hh);
      hh = fmaf(pz, was[2][c], hh);
      ov[j2] = (_Float16)fmaxf(0.f, fmaf(hh, scs[c], shs[c]));
    }
    *(half8*)&Alds[r][seg * 8] = ov;
  }
  __syncthreads();

  f32x4 acc[2][2];
#pragma unroll
  for (int fr = 0; fr < 2; ++fr)
#pragma unroll
    for (int fc = 0; fc < 2; ++fc) {
      float bv = bb[wc * 32 + fc * 16 + cl];
#pragma unroll
      for (int r = 0; r < 4; ++r) acc[fr][fc][r] = bv;
    }

#pragma unroll
  for (int kk = 0; kk < 2; ++kk) {
    half8 af[2], bf[2];
#pragma unroll
    for (int fr = 0; fr < 2; ++fr)
      af[fr] = *(const half8*)&Alds[wr*32 + fr*16 + cl][kk*32 + rq*8];
#pragma unroll
    for (int fc = 0; fc < 2; ++fc)
      bf[fc] = *(const half8*)&Wlds[wc*32 + fc*16 + cl][kk*32 + rq*8];
#pragma unroll
    for (int fr = 0; fr < 2; ++fr)
#pragma unroll
      for (int fc = 0; fc < 2; ++fc)
        acc[fr][fc] = __builtin_amdgcn_mfma_f32_16x16x32_f16(af[fr], bf[fc], acc[fr][fc], 0, 0, 0);
  }

#pragma unroll
  for (int fc = 0; fc < 2; ++fc) {
    float s = 0.f, q = 0.f, mx = -3.4e38f;
#pragma unroll
    for (int fr = 0; fr < 2; ++fr)
#pragma unroll
      for (int r = 0; r < 4; ++r) {
        float v = acc[fr][fc][r];
        s += v; q += v * v; mx = fmaxf(mx, v);
      }
    s += __shfl_xor(s, 16); q += __shfl_xor(q, 16); mx = fmaxf(mx, __shfl_xor(mx, 16));
    s += __shfl_xor(s, 32); q += __shfl_xor(q, 32); mx = fmaxf(mx, __shfl_xor(mx, 32));
    if (rq == 0) {
      int col = wc * 32 + fc * 16 + cl;
      int shdw = (rt & 15) * 256;
      atomicAdd(&redB_s[shdw + col], s);
      atomicAdd(&redB_q[shdw + col], q);
      hmax[((size_t)b * 4096 + (size_t)(rt * 2 + wr)) * 64 + col] = mx;
    }
  }
}

// ---------------- conv_a MFMA (L2/L3 edge) + fused bn1 stats; H stored fp8 ----------------
template<int CM, int KPAD>
__global__ __launch_bounds__(256) void conv_a_mfma(
    const float* __restrict__ F, int fstride, size_t fbstride,
    const int* __restrict__ idx, int idxstride,
    const u16* __restrict__ Wh,
    const float* __restrict__ T,
    u32* __restrict__ H32,
    float* __restrict__ red_s, float* __restrict__ red_q,
    int M)
{
  constexpr int FC = CM / 32;
  __shared__ u16 Alds[64][72];
  __shared__ u16 Wlds[CM][72];
  __shared__ int ji[64];
  const int t = threadIdx.x;
  const int lane = t & 63, w = t >> 6;
  const int wr = w >> 1, wc = w & 1;
  const int cl = lane & 15, rq = lane >> 4;
  const int rt = blockIdx.x, b = blockIdx.y;
  const int R0 = rt * 64;
  const float* Fb = F + (size_t)b * fbstride;

  if (t < 64) ji[t] = idx[((size_t)b * idxstride + ((R0 + t) >> 5)) * KNN + ((R0 + t) & 31)];

  f32x4 acc[2][FC];
#pragma unroll
  for (int fr = 0; fr < 2; ++fr)
#pragma unroll
    for (int fc = 0; fc < FC; ++fc) {
      int col = wc * (CM/2) + fc * 16 + cl;
#pragma unroll
      for (int r = 0; r < 4; ++r) {
        int row = R0 + wr*32 + fr*16 + rq*4 + r;
        acc[fr][fc][r] = T[((size_t)b * M + (row >> 5)) * CM + col];
      }
    }
  __syncthreads();

  for (int k0 = 0; k0 < KPAD; k0 += 64) {
    if (k0) __syncthreads();
    for (int i = t; i < 64 * 16; i += 256) {
      int r = i >> 4, seg = i & 15;
      int k = k0 + seg * 4;
      ushort4 s = {0,0,0,0};
      if (k < fstride) {
        float4 v = *(const float4*)&Fb[(size_t)ji[r] * fstride + k];
        s.x = f2h_u(v.x); s.y = f2h_u(v.y); s.z = f2h_u(v.z); s.w = f2h_u(v.w);
      }
      *(ushort4*)&Alds[r][seg * 4] = s;
    }
    for (int i = t; i < CM * 8; i += 256) {
      int o = i >> 3, seg = i & 7;
      *(float4*)&Wlds[o][seg * 8] = *(const float4*)&Wh[(size_t)o * KPAD + k0 + seg * 8];
    }
    __syncthreads();

#pragma unroll
    for (int kk = 0; kk < 2; ++kk) {
      half8 af[2], bf[FC];
#pragma unroll
      for (int fr = 0; fr < 2; ++fr)
        af[fr] = *(const half8*)&Alds[wr*32 + fr*16 + cl][kk*32 + rq*8];
#pragma unroll
      for (int fc = 0; fc < FC; ++fc)
        bf[fc] = *(const half8*)&Wlds[wc*(CM/2) + fc*16 + cl][kk*32 + rq*8];
#pragma unroll
      for (int fr = 0; fr < 2; ++fr)
#pragma unroll
        for (int fc = 0; fc < FC; ++fc)
          acc[fr][fc] = __builtin_amdgcn_mfma_f32_16x16x32_f16(af[fr], bf[fc], acc[fr][fc], 0, 0, 0);
    }
  }

  u32* Hb4 = H32 + ((size_t)b * ((size_t)M * KNN / 4) + (size_t)(R0 >> 2)) * CM;
#pragma unroll
  for (int fr = 0; fr < 2; ++fr)
#pragma unroll
    for (int fc = 0; fc < FC; ++fc) {
      int col = wc*(CM/2) + fc*16 + cl;
      u32 v = __builtin_amdgcn_cvt_pk_fp8_f32(acc[fr][fc][0], acc[fr][fc][1], 0, false);
      v = __builtin_amdgcn_cvt_pk_fp8_f32(acc[fr][fc][2], acc[fr][fc][3], v, true);
      Hb4[(size_t)(wr*8 + fr*4 + rq) * CM + col] = v;
    }

#pragma unroll
  for (int fc = 0; fc < FC; ++fc) {
    float s = 0.f, q = 0.f;
#pragma unroll
    for (int fr = 0; fr < 2; ++fr)
#pragma unroll
      for (int r = 0; r < 4; ++r) {
        float v = acc[fr][fc][r];
        s += v; q += v * v;
      }
    s += __shfl_xor(s, 16); q += __shfl_xor(q, 16);
    s += __shfl_xor(s, 32); q += __shfl_xor(q, 32);
    if (rq == 0) {
      int col = wc*(CM/2) + fc*16 + cl;
      int shdw = (rt & 15) * 256;
      atomicAdd(&red_s[shdw + col], s);
      atomicAdd(&red_q[shdw + col], q);
    }
  }
}

// ---------------- conv_b MFMA fused: 128 rows/block, inline bn1 finalize, stats2 + max ----------------
template<int CM>
__global__ __launch_bounds__(512) void conv_b_fused(
    const u32* __restrict__ H32,
    const u16* __restrict__ Wh,
    const float* __restrict__ bb,
    const float* __restrict__ gA, const float* __restrict__ beA,
    const float* __restrict__ redA_s, const float* __restrict__ redA_q, float invcnt,
    float* __restrict__ redB_s, float* __restrict__ redB_q,
    float* __restrict__ hmax,
    int Mrows)
{
  constexpr int FC = CM / 32;
  __shared__ u16 Alds[128][72];
  __shared__ u16 Wlds[CM][72];
  __shared__ float scs[CM], shs[CM];
  const int t = threadIdx.x;
  const int lane = t & 63, w = t >> 6;
  const int wr = w >> 1;
  const int wc = w & 1;
  const int cl = lane & 15, rq = lane >> 4;
  const int rt = blockIdx.x, b = blockIdx.y;
  const u32* Hb4 = H32 + ((size_t)b * ((size_t)Mrows / 4) + (size_t)(rt * 32)) * CM;

  for (int i = t; i < CM; i += 512) bn_from_red(i, redA_s, redA_q, gA, beA, invcnt, scs, shs);

  f32x4 acc[2][FC];
#pragma unroll
  for (int fr = 0; fr < 2; ++fr)
#pragma unroll
    for (int fc = 0; fc < FC; ++fc) {
      float bv = bb[wc * (CM/2) + fc * 16 + cl];
#pragma unroll
      for (int r = 0; r < 4; ++r) acc[fr][fc][r] = bv;
    }
  __syncthreads();

  for (int k0 = 0; k0 < CM; k0 += 64) {
    if (k0) __syncthreads();
    for (int i = t; i < 128 * 8; i += 512) {
      int r = i >> 3, seg = i & 7;
      int rg = r >> 2, sh8 = (r & 3) * 8;
      const u32* hp = Hb4 + (size_t)rg * CM + k0 + seg * 8;
      half8 ov;
#pragma unroll
      for (int j = 0; j < 8; ++j) {
        float v = __builtin_amdgcn_cvt_f32_fp8((hp[j] >> sh8) & 0xffu, 0);
        int c = k0 + seg * 8 + j;
        v = fmaxf(0.f, fmaf(v, scs[c], shs[c]));
        ov[j] = (_Float16)v;
      }
      *(half8*)&Alds[r][seg * 8] = ov;
    }
    for (int i = t; i < CM * 8; i += 512) {
      int o = i >> 3, seg = i & 7;
      *(float4*)&Wlds[o][seg * 8] = *(const float4*)&Wh[(size_t)o * CM + k0 + seg * 8];
    }
    __syncthreads();

#pragma unroll
    for (int kk = 0; kk < 2; ++kk) {
      half8 af[2], bf[FC];
#pragma unroll
      for (int fr = 0; fr < 2; ++fr)
        af[fr] = *(const half8*)&Alds[wr*32 + fr*16 + cl][kk*32 + rq*8];
#pragma unroll
      for (int fc = 0; fc < FC; ++fc)
        bf[fc] = *(const half8*)&Wlds[wc*(CM/2) + fc*16 + cl][kk*32 + rq*8];
#pragma unroll
      for (int fr = 0; fr < 2; ++fr)
#pragma unroll
        for (int fc = 0; fc < FC; ++fc)
          acc[fr][fc] = __builtin_amdgcn_mfma_f32_16x16x32_f16(af[fr], bf[fc], acc[fr][fc], 0, 0, 0);
    }
  }

#pragma unroll
  for (int fc = 0; fc < FC; ++fc) {
    float s = 0.f, q = 0.f, mx = -3.4e38f;
#pragma unroll
    for (int fr = 0; fr < 2; ++fr)
#pragma unroll
      for (int r = 0; r < 4; ++r) {
        float v = acc[fr][fc][r];
        s += v; q += v * v; mx = fmaxf(mx, v);
      }
    s += __shfl_xor(s, 16); q += __shfl_xor(q, 16); mx = fmaxf(mx, __shfl_xor(mx, 16));
    s += __shfl_xor(s, 32); q += __shfl_xor(q, 32); mx = fmaxf(mx, __shfl_xor(mx, 32));
    if (rq == 0) {
      int col = wc*(CM/2) + fc*16 + cl;
      int shdw = (rt & 15) * 256;
      atomicAdd(&redB_s[shdw + col], s);
      atomicAdd(&redB_q[shdw + col], q);
      hmax[((size_t)b * (Mrows >> 5) + (size_t)(rt * 4 + wr)) * CM + col] = mx;
    }
  }
}

// ---------------- bn2(inline finalize) + relu on max values -> feature buffer (+ xyz append) ----------------
__global__ __launch_bounds__(256) void bnrelu_fb(const float* __restrict__ hm,
    const float* __restrict__ gB, const float* __restrict__ beB,
    const float* __restrict__ redB_s, const float* __restrict__ redB_q, float invcnt,
    const float* __restrict__ pcd,
    float* __restrict__ fout, int CM, int fostride, size_t fobstride, int M) {
  __shared__ float scs[256], shs[256];
  for (int o = threadIdx.x; o < CM; o += 256) bn_from_red(o, redB_s, redB_q, gB, beB, invcnt, scs, shs);
  __syncthreads();
  int i = blockIdx.x * 256 + threadIdx.x;
  int cq = CM >> 2;
  int total = B8 * M * cq;
  if (i >= total) return;
  int c4 = i % cq; int r = i / cq;
  int b = r / M, m = r - b * M;
  float4 v = *(const float4*)&hm[((size_t)b * M + m) * CM + c4 * 4];
  int c = c4 * 4;
  float4 o;
  o.x = fmaxf(0.f, fmaf(v.x, scs[c],   shs[c]));
  o.y = fmaxf(0.f, fmaf(v.y, scs[c+1], shs[c+1]));
  o.z = fmaxf(0.f, fmaf(v.z, scs[c+2], shs[c+2]));
  o.w = fmaxf(0.f, fmaf(v.w, scs[c+3], shs[c+3]));
  float* op = fout + (size_t)b * fobstride + (size_t)m * fostride;
  *(float4*)(op + c) = o;
  if (pcd && c4 == 0) {
    const float* p = pcd + ((size_t)b * 4096 + m) * 3;
    *(float4*)(op + CM) = make_float4(p[0], p[1], p[2], 0.f);
  }
}

// ---------------- final FC + feat transpose ----------------
__global__ __launch_bounds__(256) void fc_out(const float* __restrict__ f4,
                                              const float* __restrict__ fcW, const float* __restrict__ fcb,
                                              float* __restrict__ out1, float* __restrict__ out3) {
  __shared__ float tile[32 * 257];
  const int t = threadIdx.x, b = blockIdx.x, n0 = blockIdx.y * 32;
  for (int i = t; i < 32 * 256; i += 256) {
    int n = i >> 8, c = i & 255;
    tile[n * 257 + c] = f4[((size_t)b * 1024 + n0 + n) * 256 + c];
  }
  __syncthreads();
  const int n = t & 31, og = t >> 5;
#pragma unroll
  for (int ci = 0; ci < 32; ++ci) {
    int c = og * 32 + ci;
    out3[((size_t)b * 256 + c) * 1024 + n0 + n] = tile[n * 257 + c];
  }
#pragma unroll
  for (int oi = 0; oi < 16; ++oi) {
    int o = og * 16 + oi;
    float acc = fcb[o];
    const float* w = fcW + (size_t)o * 256;
#pragma unroll 4
    for (int c = 0; c < 256; ++c) acc = fmaf(tile[n * 257 + c], w[c], acc);
    out1[((size_t)b * 128 + o) * 1024 + n0 + n] = acc;
  }
}

__global__ void out_xyz_idx(const float* __restrict__ pcd, float* __restrict__ out0,
                            float* __restrict__ out2) {
  int i = blockIdx.x * 256 + threadIdx.x;
  if (i < B8 * 1024) {
    int b = i >> 10, n = i & 1023;
    const float* p = pcd + ((size_t)b * 4096 + n) * 3;
    float* o = out0 + (size_t)i * 3;
    o[0] = p[0]; o[1] = p[1]; o[2] = p[2];
    out2[i] = (float)n;
  }
}

// ---------------- host ----------------
extern "C" void kernel_launch(void* const* d_in, const int* in_sizes, int n_in,
                              void* d_out, int out_size, void* d_ws, size_t ws_size,
                              hipStream_t stream) {
  (void)in_sizes; (void)n_in; (void)out_size; (void)ws_size;
  const float* pcd = (const float*)d_in[0];
  const float* W1a = (const float*)d_in[1];  const float* b1a = (const float*)d_in[2];
  const float* g1a = (const float*)d_in[3];  const float* be1a= (const float*)d_in[4];
  const float* W1b = (const float*)d_in[5];  const float* b1b = (const float*)d_in[6];
  const float* g1b = (const float*)d_in[7];  const float* be1b= (const float*)d_in[8];
  const float* W2a = (const float*)d_in[9];  const float* b2a = (const float*)d_in[10];
  const float* g2a = (const float*)d_in[11]; const float* be2a= (const float*)d_in[12];
  const float* W2b = (const float*)d_in[13]; const float* b2b = (const float*)d_in[14];
  const float* g2b = (const float*)d_in[15]; const float* be2b= (const float*)d_in[16];
  const float* W3a = (const float*)d_in[17]; const float* b3a = (const float*)d_in[18];
  const float* g3a = (const float*)d_in[19]; const float* be3a= (const float*)d_in[20];
  const float* W3b = (const float*)d_in[21]; const float* b3b = (const float*)d_in[22];
  const float* g3b = (const float*)d_in[23]; const float* be3b= (const float*)d_in[24];
  const float* fcW = (const float*)d_in[25]; const float* fcb = (const float*)d_in[26];

  float* wsf = (float*)d_ws;
  float* FB2 = wsf;                         // 8*4096*68
  float* FB3 = FB2 + 2228224;               // 8*2048*132
  float* FB4 = FB3 + 2162688;               // 8*1024*256
  float* TBUF= FB4 + 2097152;               // 8*4096*64
  float* RED = TBUF + 2097152;              // 6 x 8192
  float* R1A = RED;          float* R1B = RED + 8192;
  float* R2A = RED + 16384;  float* R2B = RED + 24576;
  float* R3A = RED + 32768;  float* R3B = RED + 40960;
  float* WAT1 = RED + 49152;
  float* WBT1 = WAT1 + 256;
  float* WBT2 = WBT1 + 256;
  float* WBT3 = WBT2 + 8704;
  float* HMAX = WBT3 + 33792;               // 8*4096*64
  int* IDX1 = (int*)(HMAX + 2097152);       // 8*4096*32
  int* IDX3 = IDX1 + (size_t)8 * 4096 * 32; // 8*1024*32
  u32* H32  = (u32*)(IDX3 + (size_t)8 * 1024 * 32); // 64 MiB fp8 H
  u16* WBH1 = (u16*)(H32 + 16777216);
  u16* WAH2 = WBH1 + 4096;
  u16* WBH2 = WAH2 + 16384;
  u16* WAH3 = WBH2 + 16384;
  u16* WBH3 = WAH3 + 49152;

  float* out0 = (float*)d_out;
  float* out1 = out0 + 24576;
  float* out2 = out1 + 1048576;
  float* out3 = out2 + 8192;

  prep_all<<<64, 256, 0, stream>>>(W1a, W1b, W2a, W2b, W3a, W3b, RED,
                                   WAT1, WBT1, WBH1, WBT2, WAH2, WBH2, WBT3, WAH3, WBH3);

  // ================ Layer 1: C2=3, CM=64, M=4096, N=4096 ================
  knn_kernel<<<dim3(1024, 8), 256, 0, stream>>>(pcd, 4096, 4096, IDX1);
  conv_a_gemm<3,64,0><<<dim3(64,1,8),256,0,stream>>>(pcd,(size_t)12288,nullptr,WBT1,b1a,nullptr,TBUF,nullptr,nullptr,4096);
  conv_a_gemm<3,64,1><<<dim3(2048,1,8),256,0,stream>>>(pcd,(size_t)12288,IDX1,WAT1,nullptr,TBUF,nullptr,R1A,R1A+4096,4096);
  l1_convb<<<dim3(2048,8),256,0,stream>>>(pcd,IDX1,WAT1,TBUF,WBH1,b1b,g1a,be1a,R1A,R1A+4096,R1B,R1B+4096,HMAX);
  bnrelu_fb<<<2048,256,0,stream>>>(HMAX,g1b,be1b,R1B,R1B+4096,1.f/1048576.f,pcd,FB2,64,68,(size_t)278528,4096);

  // ================ Layer 2: C2=67, CM=128, M=2048, N=4096  (IDX2 == IDX1[:, :2048]) ================
  conv_a_gemm<67,128,0><<<dim3(32,2,8),256,0,stream>>>(FB2,(size_t)278528,nullptr,WBT2,b2a,nullptr,TBUF,nullptr,nullptr,2048);
  conv_a_mfma<128,128><<<dim3(1024,8),256,0,stream>>>(FB2,68,(size_t)278528,IDX1,4096,WAH2,TBUF,H32,R2A,R2A+4096,2048);
  conv_b_fused<128><<<dim3(512,8),512,0,stream>>>(H32,WBH2,b2b,g2a,be2a,R2A,R2A+4096,1.f/524288.f,R2B,R2B+4096,HMAX,2048*32);
  bnrelu_fb<<<2048,256,0,stream>>>(HMAX,g2b,be2b,R2B,R2B+4096,1.f/524288.f,pcd,FB3,128,132,(size_t)270336,2048);

  // ================ Layer 3: C2=131, CM=256, M=1024, N=2048 ================
  knn_kernel<<<dim3(256, 8), 256, 0, stream>>>(pcd, 2048, 1024, IDX3);
  conv_a_gemm<131,256,0><<<dim3(16,4,8),256,0,stream>>>(FB3,(size_t)270336,nullptr,WBT3,b3a,nullptr,TBUF,nullptr,nullptr,1024);
  conv_a_mfma<256,192><<<dim3(512,8),256,0,stream>>>(FB3,132,(size_t)270336,IDX3,1024,WAH3,TBUF,H32,R3A,R3A+4096,1024);
  conv_b_fused<256><<<dim3(256,8),512,0,stream>>>(H32,WBH3,b3b,g3a,be3a,R3A,R3A+4096,1.f/262144.f,R3B,R3B+4096,HMAX,1024*32);
  bnrelu_fb<<<2048,256,0,stream>>>(HMAX,g3b,be3b,R3B,R3B+4096,1.f/262144.f,nullptr,FB4,256,256,(size_t)262144,1024);

  // ================ outputs ================
  fc_out<<<dim3(8, 32), 256, 0, stream>>>(FB4, fcW, fcb, out1, out3);
  out_xyz_idx<<<32, 256, 0, stream>>>(pcd, out0, out2);
}

// Round 14
// 749.197 us; speedup vs baseline: 1.1657x; 1.0057x over previous
//
#include <hip/hip_runtime.h>
#include <hip/hip_bf16.h>

#define B8 8
#define KNN 32
typedef unsigned short u16;
typedef unsigned int u32;
typedef unsigned long long u64;

typedef __attribute__((ext_vector_type(8))) _Float16 half8;
typedef __attribute__((ext_vector_type(4))) float f32x4;

static __device__ __forceinline__ u16 f2h_u(float f) {
  _Float16 h = (_Float16)f; u16 u; __builtin_memcpy(&u, &h, 2); return u;
}
static __device__ __forceinline__ float h2f_u(u16 u) {
  _Float16 h; __builtin_memcpy(&h, &u, 2); return (float)h;
}

// monotonic (distance, id) -> u64 key
static __device__ __forceinline__ u64 enc_key(float d, int id) {
  u32 u = __float_as_uint(d);
  u = (d >= 0.f) ? (u | 0x80000000u) : ~u;
  return ((u64)u << 32) | (u32)id;
}
static __device__ __forceinline__ float dec_val(u64 k) {
  u32 u = (u32)(k >> 32);
  u = (u & 0x80000000u) ? (u & 0x7fffffffu) : ~u;
  return __uint_as_float(u);
}

// rank-redistribute 64 keys (one per lane) -> sorted across lanes; sets tau = 32nd
static __device__ __forceinline__ u64 rank64(u64 mk, int lane, u64* slk, u64* outk, float& tau) {
  slk[lane] = mk;
  int r = 0;
#pragma unroll 16
  for (int j = 0; j < 64; ++j) r += (slk[j] < mk) ? 1 : 0;
  outk[r] = mk;
  u64 res = outk[lane];
  tau = dec_val(outk[31]);
  return res;
}

// per-block BN finalize from 16-shadow sums
static __device__ __forceinline__ void bn_from_red(int o, const float* red_s, const float* red_q,
                                                   const float* g, const float* be, float invcnt,
                                                   float* scs, float* shs) {
  float s = 0.f, q = 0.f;
#pragma unroll
  for (int i = 0; i < 16; ++i) { s += red_s[i * 256 + o]; q += red_q[i * 256 + o]; }
  float mu  = s * invcnt;
  float var = fmaxf(q * invcnt - mu * mu, 0.f);
  float scv = g[o] * rsqrtf(var + 1e-5f);
  scs[o] = scv;
  shs[o] = fmaf(-mu, scv, be[o]);
}

// ---------------- KNN (round-10 winner, frozen) ----------------
__global__ __launch_bounds__(256) void knn_kernel(const float* __restrict__ pcd,
                                                  int N, int M, int* __restrict__ idxout) {
  __shared__ float4 pts[1024];
  __shared__ u64 bufk[4][32];
  __shared__ u64 slk[4][64];
  __shared__ u64 outk[4][64];
  const int t = threadIdx.x;
  const int lane = t & 63, w = t >> 6;
  const int b = blockIdx.y;
  const int m = blockIdx.x * 4 + w;
  const float* base = pcd + (size_t)b * 12288;
  const float qx = base[m*3], qy = base[m*3+1], qz = base[m*3+2];
  const float ax = -2.f*qx, ay = -2.f*qy, az = -2.f*qz;

  u64 heldk; float tau; int cnt = 0;

  for (int i = t; i < 1024; i += 256) {
    const float* p = base + (size_t)i * 3;
    float x = p[0], y = p[1], z = p[2];
    pts[i] = make_float4(x, y, z, x*x + y*y + z*z);
  }
  __syncthreads();

  {
    float4 p = pts[lane];
    float r0 = fmaf(ax, p.x, fmaf(ay, p.y, fmaf(az, p.z, p.w)));
    heldk = rank64(enc_key(r0, lane), lane, slk[w], outk[w], tau);
  }

  for (int n0 = 0; n0 < N; n0 += 1024) {
    if (n0) {
      __syncthreads();
      for (int i = t; i < 1024; i += 256) {
        const float* p = base + (size_t)(n0 + i) * 3;
        float x = p[0], y = p[1], z = p[2];
        pts[i] = make_float4(x, y, z, x*x + y*y + z*z);
      }
      __syncthreads();
    }
    for (int c = 0; c < 1024; c += 256) {
      float4 p0 = pts[c + lane];
      float4 p1 = pts[c + 64 + lane];
      float4 p2 = pts[c + 128 + lane];
      float4 p3 = pts[c + 192 + lane];
      float r[4];
      r[0] = fmaf(ax, p0.x, fmaf(ay, p0.y, fmaf(az, p0.z, p0.w)));
      r[1] = fmaf(ax, p1.x, fmaf(ay, p1.y, fmaf(az, p1.z, p1.w)));
      r[2] = fmaf(ax, p2.x, fmaf(ay, p2.y, fmaf(az, p2.z, p2.w)));
      r[3] = fmaf(ax, p3.x, fmaf(ay, p3.y, fmaf(az, p3.z, p3.w)));
      if (n0 == 0 && c == 0) r[0] = 3.4e38f;
      float rmn = fminf(fminf(r[0], r[1]), fminf(r[2], r[3]));
      if (!__any(rmn < tau)) continue;
#pragma unroll
      for (int j = 0; j < 4; ++j) {
        float rr = r[j];
        if (!__any(rr < tau)) continue;
        int gid = n0 + c + j * 64 + lane;
        bool pass = rr < tau;
        while (__any(pass)) {
          u64 mk_ = __ballot(pass);
          int before = __popcll(mk_ & ((1ull << lane) - 1ull));
          int total  = __popcll(mk_);
          int room = 32 - cnt;
          if (pass && before < room) {
            bufk[w][cnt + before] = enc_key(rr, gid);
            pass = false;
          }
          if (total >= room) {
            u64 mk = (lane < 32) ? heldk : bufk[w][lane - 32];
            heldk = rank64(mk, lane, slk[w], outk[w], tau);
            cnt = 0;
            pass = pass && (rr < tau);
          } else {
            cnt += total;
          }
        }
      }
    }
  }
  if (cnt > 0) {
    int bl = lane - 32;
    u64 mk = (lane < 32) ? heldk
             : ((bl < cnt) ? bufk[w][bl]
                           : ((0xFFFFFFFFull << 32) | (0xFFFFFF00u | (u32)lane)));
    heldk = rank64(mk, lane, slk[w], outk[w], tau);
  }
  if (lane < KNN) idxout[((size_t)b * M + m) * KNN + lane] = (int)(u32)(heldk & 0xFFFFFFFFu);
}

// ---------------- prep_all ----------------
__global__ void prep_all(
    const float* __restrict__ W1a, const float* __restrict__ W1b,
    const float* __restrict__ W2a, const float* __restrict__ W2b,
    const float* __restrict__ W3a, const float* __restrict__ W3b,
    float* __restrict__ RED,
    float* __restrict__ WAT1, float* __restrict__ WBT1, u16* __restrict__ WBH1,
    float* __restrict__ WBT2, u16* __restrict__ WAH2, u16* __restrict__ WBH2,
    float* __restrict__ WBT3, u16* __restrict__ WAH3, u16* __restrict__ WBH3)
{
  int i0 = blockIdx.x * 256 + threadIdx.x;
  int NT = gridDim.x * 256;
  for (int i = i0; i < 49152; i += NT) RED[i] = 0.f;
  for (int i = i0; i < 256; i += NT) {
    int c = i >> 6, o = i & 63;
    float w1 = (c < 3) ? W1a[o*6 + c] : 0.f;
    float w2 = (c < 3) ? W1a[o*6 + 3 + c] : 0.f;
    WAT1[i] = w1; WBT1[i] = w2 - w1;
  }
  for (int i = i0; i < 4096; i += NT) WBH1[i] = f2h_u(W1b[i]);
  for (int i = i0; i < 68*128; i += NT) {
    int c = i >> 7, o = i & 127;
    float w1 = 0.f, w2 = 0.f;
    if (c < 67) { w1 = W2a[o*134 + c]; w2 = W2a[o*134 + 67 + c]; }
    WBT2[i] = w2 - w1;
  }
  for (int i = i0; i < 128*128; i += NT) {
    int o = i >> 7, k = i & 127;
    WAH2[i] = (k < 67) ? f2h_u(W2a[o*134 + k]) : (u16)0;
  }
  for (int i = i0; i < 16384; i += NT) WBH2[i] = f2h_u(W2b[i]);
  for (int i = i0; i < 132*256; i += NT) {
    int c = i >> 8, o = i & 255;
    float w1 = 0.f, w2 = 0.f;
    if (c < 131) { w1 = W3a[o*262 + c]; w2 = W3a[o*262 + 131 + c]; }
    WBT3[i] = w2 - w1;
  }
  for (int i = i0; i < 256*192; i += NT) {
    int o = i / 192, k = i - o * 192;
    WAH3[i] = (k < 131) ? f2h_u(W3a[o*262 + k]) : (u16)0;
  }
  for (int i = i0; i < 65536; i += NT) WBH3[i] = f2h_u(W3b[i]);
}

// ---------------- conv_a VALU GEMM: MODE 0 = T-pass; MODE 1 = L1 edge stats-only ----------------
// F16: feature source is u16 half (stride frs elems); else fp32 (stride frs elems)
template<int C2, int CM, int MODE, int F16>
__global__ __launch_bounds__(256) void conv_a_gemm(
    const void* __restrict__ F, int frs, size_t fbstride,
    const int* __restrict__ idx,
    const float* __restrict__ Wt,
    const float* __restrict__ bias,
    const float* __restrict__ T,
    float* __restrict__ Tout,
    float* __restrict__ red_s, float* __restrict__ red_q,
    int M)
{
  constexpr int KP = (C2 + 3) & ~3;
  constexpr int KC = (KP <= 68) ? KP : 44;
  __shared__ float At[64][KC];
  __shared__ float Wts[KC][64];
  __shared__ int ji[64];
  __shared__ float sred[4][64];
  __shared__ float qred[4][64];
  const int t = threadIdx.x;
  const int rt = blockIdx.x, ot = blockIdx.y, b = blockIdx.z;
  const int R0 = rt * 64, oc0 = ot * 64;

  if (t < 64) {
    int gr = R0 + t;
    ji[t] = (MODE == 0) ? gr : idx[((size_t)b * M + (gr >> 5)) * KNN + (gr & 31)];
  }

  const int cg = t & 15, rg = t >> 4;
  const int r0 = rg * 4, c0 = cg * 4;
  float acc[4][4];
  if (MODE == 0) {
#pragma unroll
    for (int j = 0; j < 4; ++j) {
      float bv = bias[oc0 + c0 + j];
#pragma unroll
      for (int i = 0; i < 4; ++i) acc[i][j] = bv;
    }
  } else {
#pragma unroll
    for (int i = 0; i < 4; ++i) {
      const float* tp = T + ((size_t)b * M + (size_t)((R0 + r0 + i) >> 5)) * CM + oc0 + c0;
      acc[i][0] = tp[0]; acc[i][1] = tp[1]; acc[i][2] = tp[2]; acc[i][3] = tp[3];
    }
  }
  __syncthreads();

  for (int k0 = 0; k0 < KP; k0 += KC) {
    if (k0) __syncthreads();
    for (int i = t; i < KC * 64; i += 256) {
      int c = i >> 6, o = i & 63;
      Wts[c][o] = Wt[(size_t)(k0 + c) * CM + oc0 + o];
    }
    if constexpr (C2 == 3) {
      const float* Fb = (const float*)F + (size_t)b * fbstride;
      for (int i = t; i < 64 * 4; i += 256) {
        int r = i >> 2, c = i & 3;
        At[r][c] = (c < 3) ? Fb[(size_t)ji[r] * 3 + c] : 0.f;
      }
    } else if constexpr (F16) {
      const u16* Fb = (const u16*)F + (size_t)b * fbstride;
      constexpr int C4 = KC / 4;
      for (int i = t; i < 64 * C4; i += 256) {
        int r = i / C4, c4 = i - r * C4;
        ushort4 v = *(const ushort4*)&Fb[(size_t)ji[r] * frs + k0 + c4 * 4];
        At[r][c4*4]   = h2f_u(v.x);
        At[r][c4*4+1] = h2f_u(v.y);
        At[r][c4*4+2] = h2f_u(v.z);
        At[r][c4*4+3] = h2f_u(v.w);
      }
    } else {
      const float* Fb = (const float*)F + (size_t)b * fbstride;
      constexpr int C4 = KC / 4;
      for (int i = t; i < 64 * C4; i += 256) {
        int r = i / C4, c4 = i - r * C4;
        *(float4*)&At[r][c4 * 4] = *(const float4*)&Fb[(size_t)ji[r] * frs + k0 + c4 * 4];
      }
    }
    __syncthreads();

#pragma unroll 4
    for (int k = 0; k < KC; ++k) {
      const float4 w4 = *(const float4*)&Wts[k][c0];
      float a0 = At[r0][k], a1 = At[r0+1][k], a2 = At[r0+2][k], a3 = At[r0+3][k];
      acc[0][0]=fmaf(a0,w4.x,acc[0][0]); acc[0][1]=fmaf(a0,w4.y,acc[0][1]);
      acc[0][2]=fmaf(a0,w4.z,acc[0][2]); acc[0][3]=fmaf(a0,w4.w,acc[0][3]);
      acc[1][0]=fmaf(a1,w4.x,acc[1][0]); acc[1][1]=fmaf(a1,w4.y,acc[1][1]);
      acc[1][2]=fmaf(a1,w4.z,acc[1][2]); acc[1][3]=fmaf(a1,w4.w,acc[1][3]);
      acc[2][0]=fmaf(a2,w4.x,acc[2][0]); acc[2][1]=fmaf(a2,w4.y,acc[2][1]);
      acc[2][2]=fmaf(a2,w4.z,acc[2][2]); acc[2][3]=fmaf(a2,w4.w,acc[2][3]);
      acc[3][0]=fmaf(a3,w4.x,acc[3][0]); acc[3][1]=fmaf(a3,w4.y,acc[3][1]);
      acc[3][2]=fmaf(a3,w4.z,acc[3][2]); acc[3][3]=fmaf(a3,w4.w,acc[3][3]);
    }
  }

  if (MODE == 0) {
    float* op = Tout + ((size_t)b * M + R0) * (size_t)CM + oc0;
#pragma unroll
    for (int i = 0; i < 4; ++i) {
      float* p = op + (size_t)(r0 + i) * CM + c0;
      p[0]=acc[i][0]; p[1]=acc[i][1]; p[2]=acc[i][2]; p[3]=acc[i][3];
    }
  } else {
    float cs[4], cq_[4];
#pragma unroll
    for (int j = 0; j < 4; ++j) {
      float s = acc[0][j] + acc[1][j] + acc[2][j] + acc[3][j];
      float q = acc[0][j]*acc[0][j] + acc[1][j]*acc[1][j] + acc[2][j]*acc[2][j] + acc[3][j]*acc[3][j];
      s += __shfl_xor(s, 16); q += __shfl_xor(q, 16);
      s += __shfl_xor(s, 32); q += __shfl_xor(q, 32);
      cs[j] = s; cq_[j] = q;
    }
    const int wv = t >> 6;
    if ((t & 48) == 0) {
#pragma unroll
      for (int j = 0; j < 4; ++j) { sred[wv][c0 + j] = cs[j]; qred[wv][c0 + j] = cq_[j]; }
    }
    __syncthreads();
    if (t < 64) {
      float s = sred[0][t] + sred[1][t] + sred[2][t] + sred[3][t];
      float q = qred[0][t] + qred[1][t] + qred[2][t] + qred[3][t];
      int shdw = (rt & 15) * 256;
      atomicAdd(&red_s[shdw + t], s);
      atomicAdd(&red_q[shdw + t], q);
    }
  }
}

// ---------------- l1_convb ----------------
__global__ __launch_bounds__(256) void l1_convb(
    const float* __restrict__ pcd,
    const int* __restrict__ idx,
    const float* __restrict__ WAT,
    const float* __restrict__ T,
    const u16* __restrict__ Wbh,
    const float* __restrict__ bb,
    const float* __restrict__ gA, const float* __restrict__ beA,
    const float* __restrict__ redA_s, const float* __restrict__ redA_q,
    float* __restrict__ redB_s, float* __restrict__ redB_q,
    float* __restrict__ hmax)
{
  __shared__ u16 Alds[64][72];
  __shared__ u16 Wlds[64][72];
  __shared__ float xyzs[64][4];
  __shared__ float was[3][64];
  __shared__ float scs[64], shs[64];
  __shared__ int ji[64];
  const int t = threadIdx.x;
  const int lane = t & 63, w = t >> 6;
  const int wr = w >> 1, wc = w & 1;
  const int cl = lane & 15, rq = lane >> 4;
  const int rt = blockIdx.x, b = blockIdx.y;
  const int R0 = rt * 64;
  const float* pb = pcd + (size_t)b * 12288;

  if (t < 64) ji[t] = idx[((size_t)b * 4096 + ((R0 + t) >> 5)) * KNN + ((R0 + t) & 31)];
  if (t < 192) was[t / 64][t & 63] = WAT[t];
  if (t >= 192) bn_from_red(t - 192, redA_s, redA_q, gA, beA, 1.f/1048576.f, scs, shs);
  for (int i = t; i < 64 * 8; i += 256) {
    int o = i >> 3, seg = i & 7;
    *(float4*)&Wlds[o][seg * 8] = *(const float4*)&Wbh[(size_t)o * 64 + seg * 8];
  }
  __syncthreads();
  if (t < 64) {
    const float* p = pb + (size_t)ji[t] * 3;
    xyzs[t][0] = p[0]; xyzs[t][1] = p[1]; xyzs[t][2] = p[2]; xyzs[t][3] = 0.f;
  }
  __syncthreads();

  for (int i = t; i < 64 * 8; i += 256) {
    int r = i >> 3, seg = i & 7;
    float px = xyzs[r][0], py = xyzs[r][1], pz = xyzs[r][2];
    const float* Tm = T + ((size_t)b * 4096 + (size_t)((R0 + r) >> 5)) * 64;
    half8 ov;
#pragma unroll
    for (int j2 = 0; j2 < 8; ++j2) {
      int c = seg * 8 + j2;
      float hh = Tm[c];
      hh = fmaf(px, was[0][c], hh);
      hh = fmaf(py, was[1][c], hh);
      hh = fmaf(pz, was[2][c], hh);
      ov[j2] = (_Float16)fmaxf(0.f, fmaf(hh, scs[c], shs[c]));
    }
    *(half8*)&Alds[r][seg * 8] = ov;
  }
  __syncthreads();

  f32x4 acc[2][2];
#pragma unroll
  for (int fr = 0; fr < 2; ++fr)
#pragma unroll
    for (int fc = 0; fc < 2; ++fc) {
      float bv = bb[wc * 32 + fc * 16 + cl];
#pragma unroll
      for (int r = 0; r < 4; ++r) acc[fr][fc][r] = bv;
    }

#pragma unroll
  for (int kk = 0; kk < 2; ++kk) {
    half8 af[2], bf[2];
#pragma unroll
    for (int fr = 0; fr < 2; ++fr)
      af[fr] = *(const half8*)&Alds[wr*32 + fr*16 + cl][kk*32 + rq*8];
#pragma unroll
    for (int fc = 0; fc < 2; ++fc)
      bf[fc] = *(const half8*)&Wlds[wc*32 + fc*16 + cl][kk*32 + rq*8];
#pragma unroll
    for (int fr = 0; fr < 2; ++fr)
#pragma unroll
      for (int fc = 0; fc < 2; ++fc)
        acc[fr][fc] = __builtin_amdgcn_mfma_f32_16x16x32_f16(af[fr], bf[fc], acc[fr][fc], 0, 0, 0);
  }

#pragma unroll
  for (int fc = 0; fc < 2; ++fc) {
    float s = 0.f, q = 0.f, mx = -3.4e38f;
#pragma unroll
    for (int fr = 0; fr < 2; ++fr)
#pragma unroll
      for (int r = 0; r < 4; ++r) {
        float v = acc[fr][fc][r];
        s += v; q += v * v; mx = fmaxf(mx, v);
      }
    s += __shfl_xor(s, 16); q += __shfl_xor(q, 16); mx = fmaxf(mx, __shfl_xor(mx, 16));
    s += __shfl_xor(s, 32); q += __shfl_xor(q, 32); mx = fmaxf(mx, __shfl_xor(mx, 32));
    if (rq == 0) {
      int col = wc * 32 + fc * 16 + cl;
      int shdw = (rt & 15) * 256;
      atomicAdd(&redB_s[shdw + col], s);
      atomicAdd(&redB_q[shdw + col], q);
      hmax[((size_t)b * 4096 + (size_t)(rt * 2 + wr)) * 64 + col] = mx;
    }
  }
}

// ---------------- conv_a MFMA (L2/L3 edge): f16 gather, fp8 H out, fused bn1 stats ----------------
template<int CM, int KPAD>
__global__ __launch_bounds__(256) void conv_a_mfma(
    const u16* __restrict__ F, int frs, size_t fbstride,
    const int* __restrict__ idx, int idxstride,
    const u16* __restrict__ Wh,
    const float* __restrict__ T,
    u32* __restrict__ H32,
    float* __restrict__ red_s, float* __restrict__ red_q,
    int M)
{
  constexpr int FC = CM / 32;
  __shared__ u16 Alds[64][72];
  __shared__ u16 Wlds[CM][72];
  __shared__ int ji[64];
  const int t = threadIdx.x;
  const int lane = t & 63, w = t >> 6;
  const int wr = w >> 1, wc = w & 1;
  const int cl = lane & 15, rq = lane >> 4;
  const int rt = blockIdx.x, b = blockIdx.y;
  const int R0 = rt * 64;
  const u16* Fb = F + (size_t)b * fbstride;

  if (t < 64) ji[t] = idx[((size_t)b * idxstride + ((R0 + t) >> 5)) * KNN + ((R0 + t) & 31)];

  f32x4 acc[2][FC];
#pragma unroll
  for (int fr = 0; fr < 2; ++fr)
#pragma unroll
    for (int fc = 0; fc < FC; ++fc) {
      int col = wc * (CM/2) + fc * 16 + cl;
#pragma unroll
      for (int r = 0; r < 4; ++r) {
        int row = R0 + wr*32 + fr*16 + rq*4 + r;
        acc[fr][fc][r] = T[((size_t)b * M + (row >> 5)) * CM + col];
      }
    }
  __syncthreads();

  for (int k0 = 0; k0 < KPAD; k0 += 64) {
    if (k0) __syncthreads();
    for (int i = t; i < 64 * 16; i += 256) {
      int r = i >> 4, seg = i & 15;
      int k = k0 + seg * 4;
      ushort4 s = {0,0,0,0};
      if (k < frs) s = *(const ushort4*)&Fb[(size_t)ji[r] * frs + k];
      *(ushort4*)&Alds[r][seg * 4] = s;
    }
    for (int i = t; i < CM * 8; i += 256) {
      int o = i >> 3, seg = i & 7;
      *(float4*)&Wlds[o][seg * 8] = *(const float4*)&Wh[(size_t)o * KPAD + k0 + seg * 8];
    }
    __syncthreads();

#pragma unroll
    for (int kk = 0; kk < 2; ++kk) {
      half8 af[2], bf[FC];
#pragma unroll
      for (int fr = 0; fr < 2; ++fr)
        af[fr] = *(const half8*)&Alds[wr*32 + fr*16 + cl][kk*32 + rq*8];
#pragma unroll
      for (int fc = 0; fc < FC; ++fc)
        bf[fc] = *(const half8*)&Wlds[wc*(CM/2) + fc*16 + cl][kk*32 + rq*8];
#pragma unroll
      for (int fr = 0; fr < 2; ++fr)
#pragma unroll
        for (int fc = 0; fc < FC; ++fc)
          acc[fr][fc] = __builtin_amdgcn_mfma_f32_16x16x32_f16(af[fr], bf[fc], acc[fr][fc], 0, 0, 0);
    }
  }

  u32* Hb4 = H32 + ((size_t)b * ((size_t)M * KNN / 4) + (size_t)(R0 >> 2)) * CM;
#pragma unroll
  for (int fr = 0; fr < 2; ++fr)
#pragma unroll
    for (int fc = 0; fc < FC; ++fc) {
      int col = wc*(CM/2) + fc*16 + cl;
      u32 v = __builtin_amdgcn_cvt_pk_fp8_f32(acc[fr][fc][0], acc[fr][fc][1], 0, false);
      v = __builtin_amdgcn_cvt_pk_fp8_f32(acc[fr][fc][2], acc[fr][fc][3], v, true);
      Hb4[(size_t)(wr*8 + fr*4 + rq) * CM + col] = v;
    }

#pragma unroll
  for (int fc = 0; fc < FC; ++fc) {
    float s = 0.f, q = 0.f;
#pragma unroll
    for (int fr = 0; fr < 2; ++fr)
#pragma unroll
      for (int r = 0; r < 4; ++r) {
        float v = acc[fr][fc][r];
        s += v; q += v * v;
      }
    s += __shfl_xor(s, 16); q += __shfl_xor(q, 16);
    s += __shfl_xor(s, 32); q += __shfl_xor(q, 32);
    if (rq == 0) {
      int col = wc*(CM/2) + fc*16 + cl;
      int shdw = (rt & 15) * 256;
      atomicAdd(&red_s[shdw + col], s);
      atomicAdd(&red_q[shdw + col], q);
    }
  }
}

// ---------------- conv_b MFMA fused: 128 rows/block ----------------
template<int CM>
__global__ __launch_bounds__(512) void conv_b_fused(
    const u32* __restrict__ H32,
    const u16* __restrict__ Wh,
    const float* __restrict__ bb,
    const float* __restrict__ gA, const float* __restrict__ beA,
    const float* __restrict__ redA_s, const float* __restrict__ redA_q, float invcnt,
    float* __restrict__ redB_s, float* __restrict__ redB_q,
    float* __restrict__ hmax,
    int Mrows)
{
  constexpr int FC = CM / 32;
  __shared__ u16 Alds[128][72];
  __shared__ u16 Wlds[CM][72];
  __shared__ float scs[CM], shs[CM];
  const int t = threadIdx.x;
  const int lane = t & 63, w = t >> 6;
  const int wr = w >> 1;
  const int wc = w & 1;
  const int cl = lane & 15, rq = lane >> 4;
  const int rt = blockIdx.x, b = blockIdx.y;
  const u32* Hb4 = H32 + ((size_t)b * ((size_t)Mrows / 4) + (size_t)(rt * 32)) * CM;

  for (int i = t; i < CM; i += 512) bn_from_red(i, redA_s, redA_q, gA, beA, invcnt, scs, shs);

  f32x4 acc[2][FC];
#pragma unroll
  for (int fr = 0; fr < 2; ++fr)
#pragma unroll
    for (int fc = 0; fc < FC; ++fc) {
      float bv = bb[wc * (CM/2) + fc * 16 + cl];
#pragma unroll
      for (int r = 0; r < 4; ++r) acc[fr][fc][r] = bv;
    }
  __syncthreads();

  for (int k0 = 0; k0 < CM; k0 += 64) {
    if (k0) __syncthreads();
    for (int i = t; i < 128 * 8; i += 512) {
      int r = i >> 3, seg = i & 7;
      int rg = r >> 2, sh8 = (r & 3) * 8;
      const u32* hp = Hb4 + (size_t)rg * CM + k0 + seg * 8;
      half8 ov;
#pragma unroll
      for (int j = 0; j < 8; ++j) {
        float v = __builtin_amdgcn_cvt_f32_fp8((hp[j] >> sh8) & 0xffu, 0);
        int c = k0 + seg * 8 + j;
        v = fmaxf(0.f, fmaf(v, scs[c], shs[c]));
        ov[j] = (_Float16)v;
      }
      *(half8*)&Alds[r][seg * 8] = ov;
    }
    for (int i = t; i < CM * 8; i += 512) {
      int o = i >> 3, seg = i & 7;
      *(float4*)&Wlds[o][seg * 8] = *(const float4*)&Wh[(size_t)o * CM + k0 + seg * 8];
    }
    __syncthreads();

#pragma unroll
    for (int kk = 0; kk < 2; ++kk) {
      half8 af[2], bf[FC];
#pragma unroll
      for (int fr = 0; fr < 2; ++fr)
        af[fr] = *(const half8*)&Alds[wr*32 + fr*16 + cl][kk*32 + rq*8];
#pragma unroll
      for (int fc = 0; fc < FC; ++fc)
        bf[fc] = *(const half8*)&Wlds[wc*(CM/2) + fc*16 + cl][kk*32 + rq*8];
#pragma unroll
      for (int fr = 0; fr < 2; ++fr)
#pragma unroll
        for (int fc = 0; fc < FC; ++fc)
          acc[fr][fc] = __builtin_amdgcn_mfma_f32_16x16x32_f16(af[fr], bf[fc], acc[fr][fc], 0, 0, 0);
    }
  }

#pragma unroll
  for (int fc = 0; fc < FC; ++fc) {
    float s = 0.f, q = 0.f, mx = -3.4e38f;
#pragma unroll
    for (int fr = 0; fr < 2; ++fr)
#pragma unroll
      for (int r = 0; r < 4; ++r) {
        float v = acc[fr][fc][r];
        s += v; q += v * v; mx = fmaxf(mx, v);
      }
    s += __shfl_xor(s, 16); q += __shfl_xor(q, 16); mx = fmaxf(mx, __shfl_xor(mx, 16));
    s += __shfl_xor(s, 32); q += __shfl_xor(q, 32); mx = fmaxf(mx, __shfl_xor(mx, 32));
    if (rq == 0) {
      int col = wc*(CM/2) + fc*16 + cl;
      int shdw = (rt & 15) * 256;
      atomicAdd(&redB_s[shdw + col], s);
      atomicAdd(&redB_q[shdw + col], q);
      hmax[((size_t)b * (Mrows >> 5) + (size_t)(rt * 4 + wr)) * CM + col] = mx;
    }
  }
}

// ---------------- bn2(inline) + relu on max -> f16 feature buffer (+ xyz append) ----------------
__global__ __launch_bounds__(256) void bnrelu_fb(const float* __restrict__ hm,
    const float* __restrict__ gB, const float* __restrict__ beB,
    const float* __restrict__ redB_s, const float* __restrict__ redB_q, float invcnt,
    const float* __restrict__ pcd,
    u16* __restrict__ fout, int CM, int fostride, size_t fobstride, int M) {
  __shared__ float scs[256], shs[256];
  for (int o = threadIdx.x; o < CM; o += 256) bn_from_red(o, redB_s, redB_q, gB, beB, invcnt, scs, shs);
  __syncthreads();
  int i = blockIdx.x * 256 + threadIdx.x;
  int cq = CM >> 2;
  int total = B8 * M * cq;
  if (i >= total) return;
  int c4 = i % cq; int r = i / cq;
  int b = r / M, m = r - b * M;
  float4 v = *(const float4*)&hm[((size_t)b * M + m) * CM + c4 * 4];
  int c = c4 * 4;
  ushort4 o;
  o.x = f2h_u(fmaxf(0.f, fmaf(v.x, scs[c],   shs[c])));
  o.y = f2h_u(fmaxf(0.f, fmaf(v.y, scs[c+1], shs[c+1])));
  o.z = f2h_u(fmaxf(0.f, fmaf(v.z, scs[c+2], shs[c+2])));
  o.w = f2h_u(fmaxf(0.f, fmaf(v.w, scs[c+3], shs[c+3])));
  u16* op = fout + (size_t)b * fobstride + (size_t)m * fostride;
  *(ushort4*)(op + c) = o;
  if (pcd && c4 == 0) {
    const float* p = pcd + ((size_t)b * 4096 + m) * 3;
    half8 xz;
    xz[0] = (_Float16)p[0]; xz[1] = (_Float16)p[1]; xz[2] = (_Float16)p[2];
    xz[3] = (_Float16)0.f; xz[4] = (_Float16)0.f; xz[5] = (_Float16)0.f;
    xz[6] = (_Float16)0.f; xz[7] = (_Float16)0.f;
    *(half8*)(op + CM) = xz;
  }
}

// ---------------- final FC + feat transpose (f16 input) ----------------
__global__ __launch_bounds__(256) void fc_out(const u16* __restrict__ f4,
                                              const float* __restrict__ fcW, const float* __restrict__ fcb,
                                              float* __restrict__ out1, float* __restrict__ out3) {
  __shared__ float tile[32 * 257];
  const int t = threadIdx.x, b = blockIdx.x, n0 = blockIdx.y * 32;
  for (int i = t; i < 32 * 64; i += 256) {
    int n = i >> 6, c4 = i & 63;
    ushort4 v = *(const ushort4*)&f4[((size_t)b * 1024 + n0 + n) * 256 + c4 * 4];
    float* tp = &tile[n * 257 + c4 * 4];
    tp[0] = h2f_u(v.x); tp[1] = h2f_u(v.y); tp[2] = h2f_u(v.z); tp[3] = h2f_u(v.w);
  }
  __syncthreads();
  const int n = t & 31, og = t >> 5;
#pragma unroll
  for (int ci = 0; ci < 32; ++ci) {
    int c = og * 32 + ci;
    out3[((size_t)b * 256 + c) * 1024 + n0 + n] = tile[n * 257 + c];
  }
#pragma unroll
  for (int oi = 0; oi < 16; ++oi) {
    int o = og * 16 + oi;
    float acc = fcb[o];
    const float* w = fcW + (size_t)o * 256;
#pragma unroll 4
    for (int c = 0; c < 256; ++c) acc = fmaf(tile[n * 257 + c], w[c], acc);
    out1[((size_t)b * 128 + o) * 1024 + n0 + n] = acc;
  }
}

__global__ void out_xyz_idx(const float* __restrict__ pcd, float* __restrict__ out0,
                            float* __restrict__ out2) {
  int i = blockIdx.x * 256 + threadIdx.x;
  if (i < B8 * 1024) {
    int b = i >> 10, n = i & 1023;
    const float* p = pcd + ((size_t)b * 4096 + n) * 3;
    float* o = out0 + (size_t)i * 3;
    o[0] = p[0]; o[1] = p[1]; o[2] = p[2];
    out2[i] = (float)n;
  }
}

// ---------------- host ----------------
extern "C" void kernel_launch(void* const* d_in, const int* in_sizes, int n_in,
                              void* d_out, int out_size, void* d_ws, size_t ws_size,
                              hipStream_t stream) {
  (void)in_sizes; (void)n_in; (void)out_size; (void)ws_size;
  const float* pcd = (const float*)d_in[0];
  const float* W1a = (const float*)d_in[1];  const float* b1a = (const float*)d_in[2];
  const float* g1a = (const float*)d_in[3];  const float* be1a= (const float*)d_in[4];
  const float* W1b = (const float*)d_in[5];  const float* b1b = (const float*)d_in[6];
  const float* g1b = (const float*)d_in[7];  const float* be1b= (const float*)d_in[8];
  const float* W2a = (const float*)d_in[9];  const float* b2a = (const float*)d_in[10];
  const float* g2a = (const float*)d_in[11]; const float* be2a= (const float*)d_in[12];
  const float* W2b = (const float*)d_in[13]; const float* b2b = (const float*)d_in[14];
  const float* g2b = (const float*)d_in[15]; const float* be2b= (const float*)d_in[16];
  const float* W3a = (const float*)d_in[17]; const float* b3a = (const float*)d_in[18];
  const float* g3a = (const float*)d_in[19]; const float* be3a= (const float*)d_in[20];
  const float* W3b = (const float*)d_in[21]; const float* b3b = (const float*)d_in[22];
  const float* g3b = (const float*)d_in[23]; const float* be3b= (const float*)d_in[24];
  const float* fcW = (const float*)d_in[25]; const float* fcb = (const float*)d_in[26];

  // f16 feature buffers
  u16* FB2h = (u16*)d_ws;                       // 8*4096*72 = 2,359,296 u16
  u16* FB3h = FB2h + 2359296;                   // 8*2048*136 = 2,228,224
  u16* FB4h = FB3h + 2228224;                   // 8*1024*256 = 2,097,152
  float* wsf = (float*)(FB4h + 2097152);
  float* TBUF= wsf;                             // 8*4096*64
  float* RED = TBUF + 2097152;                  // 6 x 8192
  float* R1A = RED;          float* R1B = RED + 8192;
  float* R2A = RED + 16384;  float* R2B = RED + 24576;
  float* R3A = RED + 32768;  float* R3B = RED + 40960;
  float* WAT1 = RED + 49152;
  float* WBT1 = WAT1 + 256;
  float* WBT2 = WBT1 + 256;
  float* WBT3 = WBT2 + 8704;
  float* HMAX = WBT3 + 33792;                   // 8*4096*64
  int* IDX1 = (int*)(HMAX + 2097152);           // 8*4096*32
  int* IDX3 = IDX1 + (size_t)8 * 4096 * 32;     // 8*1024*32
  u32* H32  = (u32*)(IDX3 + (size_t)8 * 1024 * 32); // 64 MiB fp8 H
  u16* WBH1 = (u16*)(H32 + 16777216);
  u16* WAH2 = WBH1 + 4096;
  u16* WBH2 = WAH2 + 16384;
  u16* WAH3 = WBH2 + 16384;
  u16* WBH3 = WAH3 + 49152;

  float* out0 = (float*)d_out;
  float* out1 = out0 + 24576;
  float* out2 = out1 + 1048576;
  float* out3 = out2 + 8192;

  prep_all<<<64, 256, 0, stream>>>(W1a, W1b, W2a, W2b, W3a, W3b, RED,
                                   WAT1, WBT1, WBH1, WBT2, WAH2, WBH2, WBT3, WAH3, WBH3);

  // ================ Layer 1: C2=3, CM=64, M=4096, N=4096 ================
  knn_kernel<<<dim3(1024, 8), 256, 0, stream>>>(pcd, 4096, 4096, IDX1);
  conv_a_gemm<3,64,0,0><<<dim3(64,1,8),256,0,stream>>>(pcd,3,(size_t)12288,nullptr,WBT1,b1a,nullptr,TBUF,nullptr,nullptr,4096);
  conv_a_gemm<3,64,1,0><<<dim3(2048,1,8),256,0,stream>>>(pcd,3,(size_t)12288,IDX1,WAT1,nullptr,TBUF,nullptr,R1A,R1A+4096,4096);
  l1_convb<<<dim3(2048,8),256,0,stream>>>(pcd,IDX1,WAT1,TBUF,WBH1,b1b,g1a,be1a,R1A,R1A+4096,R1B,R1B+4096,HMAX);
  bnrelu_fb<<<2048,256,0,stream>>>(HMAX,g1b,be1b,R1B,R1B+4096,1.f/1048576.f,pcd,FB2h,64,72,(size_t)294912,4096);

  // ================ Layer 2: C2=67, CM=128, M=2048, N=4096  (IDX2 == IDX1[:, :2048]) ================
  conv_a_gemm<67,128,0,1><<<dim3(32,2,8),256,0,stream>>>(FB2h,72,(size_t)294912,nullptr,WBT2,b2a,nullptr,TBUF,nullptr,nullptr,2048);
  conv_a_mfma<128,128><<<dim3(1024,8),256,0,stream>>>(FB2h,72,(size_t)294912,IDX1,4096,WAH2,TBUF,H32,R2A,R2A+4096,2048);
  conv_b_fused<128><<<dim3(512,8),512,0,stream>>>(H32,WBH2,b2b,g2a,be2a,R2A,R2A+4096,1.f/524288.f,R2B,R2B+4096,HMAX,2048*32);
  bnrelu_fb<<<2048,256,0,stream>>>(HMAX,g2b,be2b,R2B,R2B+4096,1.f/524288.f,pcd,FB3h,128,136,(size_t)278528,2048);

  // ================ Layer 3: C2=131, CM=256, M=1024, N=2048 ================
  knn_kernel<<<dim3(256, 8), 256, 0, stream>>>(pcd, 2048, 1024, IDX3);
  conv_a_gemm<131,256,0,1><<<dim3(16,4,8),256,0,stream>>>(FB3h,136,(size_t)278528,nullptr,WBT3,b3a,nullptr,TBUF,nullptr,nullptr,1024);
  conv_a_mfma<256,192><<<dim3(512,8),256,0,stream>>>(FB3h,136,(size_t)278528,IDX3,1024,WAH3,TBUF,H32,R3A,R3A+4096,1024);
  conv_b_fused<256><<<dim3(256,8),512,0,stream>>>(H32,WBH3,b3b,g3a,be3a,R3A,R3A+4096,1.f/262144.f,R3B,R3B+4096,HMAX,1024*32);
  bnrelu_fb<<<2048,256,0,stream>>>(HMAX,g3b,be3b,R3B,R3B+4096,1.f/262144.f,nullptr,FB4h,256,256,(size_t)262144,1024);

  // ================ outputs ================
  fc_out<<<dim3(8, 32), 256, 0, stream>>>(FB4h, fcW, fcb, out1, out3);
  out_xyz_idx<<<32, 256, 0, stream>>>(pcd, out0, out2);
}

// Round 15
// 730.663 us; speedup vs baseline: 1.1953x; 1.0254x over previous
//
#include <hip/hip_runtime.h>
#include <hip/hip_bf16.h>

#define B8 8
#define KNN 32
typedef unsigned short u16;
typedef unsigned int u32;
typedef unsigned long long u64;

typedef __attribute__((ext_vector_type(8))) _Float16 half8;
typedef __attribute__((ext_vector_type(4))) float f32x4;

static __device__ __forceinline__ u16 f2h_u(float f) {
  _Float16 h = (_Float16)f; u16 u; __builtin_memcpy(&u, &h, 2); return u;
}
static __device__ __forceinline__ float h2f_u(u16 u) {
  _Float16 h; __builtin_memcpy(&h, &u, 2); return (float)h;
}

// monotonic (distance, id) -> u64 key
static __device__ __forceinline__ u64 enc_key(float d, int id) {
  u32 u = __float_as_uint(d);
  u = (d >= 0.f) ? (u | 0x80000000u) : ~u;
  return ((u64)u << 32) | (u32)id;
}
static __device__ __forceinline__ float dec_val(u64 k) {
  u32 u = (u32)(k >> 32);
  u = (u & 0x80000000u) ? (u & 0x7fffffffu) : ~u;
  return __uint_as_float(u);
}

// rank-redistribute 64 keys (one per lane) -> sorted across lanes; sets tau = 32nd
static __device__ __forceinline__ u64 rank64(u64 mk, int lane, u64* slk, u64* outk, float& tau) {
  slk[lane] = mk;
  int r = 0;
#pragma unroll 16
  for (int j = 0; j < 64; ++j) r += (slk[j] < mk) ? 1 : 0;
  outk[r] = mk;
  u64 res = outk[lane];
  tau = dec_val(outk[31]);
  return res;
}

// per-block BN finalize from 16-shadow sums
static __device__ __forceinline__ void bn_from_red(int o, const float* red_s, const float* red_q,
                                                   const float* g, const float* be, float invcnt,
                                                   float* scs, float* shs) {
  float s = 0.f, q = 0.f;
#pragma unroll
  for (int i = 0; i < 16; ++i) { s += red_s[i * 256 + o]; q += red_q[i * 256 + o]; }
  float mu  = s * invcnt;
  float var = fmaxf(q * invcnt - mu * mu, 0.f);
  float scv = g[o] * rsqrtf(var + 1e-5f);
  scs[o] = scv;
  shs[o] = fmaf(-mu, scv, be[o]);
}

// ---------------- KNN: merged L1+L3 dispatch; inner loop = round-10 winner (frozen) ----------------
__global__ __launch_bounds__(256) void knn_dual(const float* __restrict__ pcd,
                                                int* __restrict__ idx1, int* __restrict__ idx3) {
  __shared__ float4 pts[1024];
  __shared__ u64 bufk[4][32];
  __shared__ u64 slk[4][64];
  __shared__ u64 outk[4][64];
  const int t = threadIdx.x;
  const int lane = t & 63, w = t >> 6;
  const int b = blockIdx.y;
  int N, M, bx; int* idxout;
  if (blockIdx.x < 1024) { N = 4096; M = 4096; bx = blockIdx.x; idxout = idx1; }
  else                   { N = 2048; M = 1024; bx = blockIdx.x - 1024; idxout = idx3; }
  const int m = bx * 4 + w;
  const float* base = pcd + (size_t)b * 12288;
  const float qx = base[m*3], qy = base[m*3+1], qz = base[m*3+2];
  const float ax = -2.f*qx, ay = -2.f*qy, az = -2.f*qz;

  u64 heldk; float tau; int cnt = 0;

  for (int i = t; i < 1024; i += 256) {
    const float* p = base + (size_t)i * 3;
    float x = p[0], y = p[1], z = p[2];
    pts[i] = make_float4(x, y, z, x*x + y*y + z*z);
  }
  __syncthreads();

  {
    float4 p = pts[lane];
    float r0 = fmaf(ax, p.x, fmaf(ay, p.y, fmaf(az, p.z, p.w)));
    heldk = rank64(enc_key(r0, lane), lane, slk[w], outk[w], tau);
  }

  for (int n0 = 0; n0 < N; n0 += 1024) {
    if (n0) {
      __syncthreads();
      for (int i = t; i < 1024; i += 256) {
        const float* p = base + (size_t)(n0 + i) * 3;
        float x = p[0], y = p[1], z = p[2];
        pts[i] = make_float4(x, y, z, x*x + y*y + z*z);
      }
      __syncthreads();
    }
    for (int c = 0; c < 1024; c += 256) {
      float4 p0 = pts[c + lane];
      float4 p1 = pts[c + 64 + lane];
      float4 p2 = pts[c + 128 + lane];
      float4 p3 = pts[c + 192 + lane];
      float r[4];
      r[0] = fmaf(ax, p0.x, fmaf(ay, p0.y, fmaf(az, p0.z, p0.w)));
      r[1] = fmaf(ax, p1.x, fmaf(ay, p1.y, fmaf(az, p1.z, p1.w)));
      r[2] = fmaf(ax, p2.x, fmaf(ay, p2.y, fmaf(az, p2.z, p2.w)));
      r[3] = fmaf(ax, p3.x, fmaf(ay, p3.y, fmaf(az, p3.z, p3.w)));
      if (n0 == 0 && c == 0) r[0] = 3.4e38f;
      float rmn = fminf(fminf(r[0], r[1]), fminf(r[2], r[3]));
      if (!__any(rmn < tau)) continue;
#pragma unroll
      for (int j = 0; j < 4; ++j) {
        float rr = r[j];
        if (!__any(rr < tau)) continue;
        int gid = n0 + c + j * 64 + lane;
        bool pass = rr < tau;
        while (__any(pass)) {
          u64 mk_ = __ballot(pass);
          int before = __popcll(mk_ & ((1ull << lane) - 1ull));
          int total  = __popcll(mk_);
          int room = 32 - cnt;
          if (pass && before < room) {
            bufk[w][cnt + before] = enc_key(rr, gid);
            pass = false;
          }
          if (total >= room) {
            u64 mk = (lane < 32) ? heldk : bufk[w][lane - 32];
            heldk = rank64(mk, lane, slk[w], outk[w], tau);
            cnt = 0;
            pass = pass && (rr < tau);
          } else {
            cnt += total;
          }
        }
      }
    }
  }
  if (cnt > 0) {
    int bl = lane - 32;
    u64 mk = (lane < 32) ? heldk
             : ((bl < cnt) ? bufk[w][bl]
                           : ((0xFFFFFFFFull << 32) | (0xFFFFFF00u | (u32)lane)));
    heldk = rank64(mk, lane, slk[w], outk[w], tau);
  }
  if (lane < KNN) idxout[((size_t)b * M + m) * KNN + lane] = (int)(u32)(heldk & 0xFFFFFFFFu);
}

// ---------------- prep_all ----------------
__global__ void prep_all(
    const float* __restrict__ W1a, const float* __restrict__ W1b,
    const float* __restrict__ W2a, const float* __restrict__ W2b,
    const float* __restrict__ W3a, const float* __restrict__ W3b,
    float* __restrict__ RED,
    float* __restrict__ WAT1, float* __restrict__ WBT1, u16* __restrict__ WBH1,
    float* __restrict__ WBT2, u16* __restrict__ WAH2, u16* __restrict__ WBH2,
    float* __restrict__ WBT3, u16* __restrict__ WAH3, u16* __restrict__ WBH3)
{
  int i0 = blockIdx.x * 256 + threadIdx.x;
  int NT = gridDim.x * 256;
  for (int i = i0; i < 49152; i += NT) RED[i] = 0.f;
  for (int i = i0; i < 256; i += NT) {
    int c = i >> 6, o = i & 63;
    float w1 = (c < 3) ? W1a[o*6 + c] : 0.f;
    float w2 = (c < 3) ? W1a[o*6 + 3 + c] : 0.f;
    WAT1[i] = w1; WBT1[i] = w2 - w1;
  }
  for (int i = i0; i < 4096; i += NT) WBH1[i] = f2h_u(W1b[i]);
  for (int i = i0; i < 68*128; i += NT) {
    int c = i >> 7, o = i & 127;
    float w1 = 0.f, w2 = 0.f;
    if (c < 67) { w1 = W2a[o*134 + c]; w2 = W2a[o*134 + 67 + c]; }
    WBT2[i] = w2 - w1;
  }
  for (int i = i0; i < 128*128; i += NT) {
    int o = i >> 7, k = i & 127;
    WAH2[i] = (k < 67) ? f2h_u(W2a[o*134 + k]) : (u16)0;
  }
  for (int i = i0; i < 16384; i += NT) WBH2[i] = f2h_u(W2b[i]);
  for (int i = i0; i < 132*256; i += NT) {
    int c = i >> 8, o = i & 255;
    float w1 = 0.f, w2 = 0.f;
    if (c < 131) { w1 = W3a[o*262 + c]; w2 = W3a[o*262 + 131 + c]; }
    WBT3[i] = w2 - w1;
  }
  for (int i = i0; i < 256*192; i += NT) {
    int o = i / 192, k = i - o * 192;
    WAH3[i] = (k < 131) ? f2h_u(W3a[o*262 + k]) : (u16)0;
  }
  for (int i = i0; i < 65536; i += NT) WBH3[i] = f2h_u(W3b[i]);
}

// ---------------- conv_a VALU GEMM: MODE 0 = T-pass; MODE 1 = L1 edge stats-only ----------------
template<int C2, int CM, int MODE, int F16>
__global__ __launch_bounds__(256) void conv_a_gemm(
    const void* __restrict__ F, int frs, size_t fbstride,
    const int* __restrict__ idx,
    const float* __restrict__ Wt,
    const float* __restrict__ bias,
    const float* __restrict__ T,
    float* __restrict__ Tout,
    float* __restrict__ red_s, float* __restrict__ red_q,
    int M)
{
  constexpr int KP = (C2 + 3) & ~3;
  constexpr int KC = (KP <= 68) ? KP : 44;
  __shared__ float At[64][KC];
  __shared__ float Wts[KC][64];
  __shared__ int ji[64];
  __shared__ float sred[4][64];
  __shared__ float qred[4][64];
  const int t = threadIdx.x;
  const int rt = blockIdx.x, ot = blockIdx.y, b = blockIdx.z;
  const int R0 = rt * 64, oc0 = ot * 64;

  if (t < 64) {
    int gr = R0 + t;
    ji[t] = (MODE == 0) ? gr : idx[((size_t)b * M + (gr >> 5)) * KNN + (gr & 31)];
  }

  const int cg = t & 15, rg = t >> 4;
  const int r0 = rg * 4, c0 = cg * 4;
  float acc[4][4];
  if (MODE == 0) {
#pragma unroll
    for (int j = 0; j < 4; ++j) {
      float bv = bias[oc0 + c0 + j];
#pragma unroll
      for (int i = 0; i < 4; ++i) acc[i][j] = bv;
    }
  } else {
#pragma unroll
    for (int i = 0; i < 4; ++i) {
      const float* tp = T + ((size_t)b * M + (size_t)((R0 + r0 + i) >> 5)) * CM + oc0 + c0;
      acc[i][0] = tp[0]; acc[i][1] = tp[1]; acc[i][2] = tp[2]; acc[i][3] = tp[3];
    }
  }
  __syncthreads();

  for (int k0 = 0; k0 < KP; k0 += KC) {
    if (k0) __syncthreads();
    for (int i = t; i < KC * 64; i += 256) {
      int c = i >> 6, o = i & 63;
      Wts[c][o] = Wt[(size_t)(k0 + c) * CM + oc0 + o];
    }
    if constexpr (C2 == 3) {
      const float* Fb = (const float*)F + (size_t)b * fbstride;
      for (int i = t; i < 64 * 4; i += 256) {
        int r = i >> 2, c = i & 3;
        At[r][c] = (c < 3) ? Fb[(size_t)ji[r] * 3 + c] : 0.f;
      }
    } else if constexpr (F16) {
      const u16* Fb = (const u16*)F + (size_t)b * fbstride;
      constexpr int C4 = KC / 4;
      for (int i = t; i < 64 * C4; i += 256) {
        int r = i / C4, c4 = i - r * C4;
        ushort4 v = *(const ushort4*)&Fb[(size_t)ji[r] * frs + k0 + c4 * 4];
        At[r][c4*4]   = h2f_u(v.x);
        At[r][c4*4+1] = h2f_u(v.y);
        At[r][c4*4+2] = h2f_u(v.z);
        At[r][c4*4+3] = h2f_u(v.w);
      }
    } else {
      const float* Fb = (const float*)F + (size_t)b * fbstride;
      constexpr int C4 = KC / 4;
      for (int i = t; i < 64 * C4; i += 256) {
        int r = i / C4, c4 = i - r * C4;
        *(float4*)&At[r][c4 * 4] = *(const float4*)&Fb[(size_t)ji[r] * frs + k0 + c4 * 4];
      }
    }
    __syncthreads();

#pragma unroll 4
    for (int k = 0; k < KC; ++k) {
      const float4 w4 = *(const float4*)&Wts[k][c0];
      float a0 = At[r0][k], a1 = At[r0+1][k], a2 = At[r0+2][k], a3 = At[r0+3][k];
      acc[0][0]=fmaf(a0,w4.x,acc[0][0]); acc[0][1]=fmaf(a0,w4.y,acc[0][1]);
      acc[0][2]=fmaf(a0,w4.z,acc[0][2]); acc[0][3]=fmaf(a0,w4.w,acc[0][3]);
      acc[1][0]=fmaf(a1,w4.x,acc[1][0]); acc[1][1]=fmaf(a1,w4.y,acc[1][1]);
      acc[1][2]=fmaf(a1,w4.z,acc[1][2]); acc[1][3]=fmaf(a1,w4.w,acc[1][3]);
      acc[2][0]=fmaf(a2,w4.x,acc[2][0]); acc[2][1]=fmaf(a2,w4.y,acc[2][1]);
      acc[2][2]=fmaf(a2,w4.z,acc[2][2]); acc[2][3]=fmaf(a2,w4.w,acc[2][3]);
      acc[3][0]=fmaf(a3,w4.x,acc[3][0]); acc[3][1]=fmaf(a3,w4.y,acc[3][1]);
      acc[3][2]=fmaf(a3,w4.z,acc[3][2]); acc[3][3]=fmaf(a3,w4.w,acc[3][3]);
    }
  }

  if (MODE == 0) {
    float* op = Tout + ((size_t)b * M + R0) * (size_t)CM + oc0;
#pragma unroll
    for (int i = 0; i < 4; ++i) {
      float* p = op + (size_t)(r0 + i) * CM + c0;
      p[0]=acc[i][0]; p[1]=acc[i][1]; p[2]=acc[i][2]; p[3]=acc[i][3];
    }
  } else {
    float cs[4], cq_[4];
#pragma unroll
    for (int j = 0; j < 4; ++j) {
      float s = acc[0][j] + acc[1][j] + acc[2][j] + acc[3][j];
      float q = acc[0][j]*acc[0][j] + acc[1][j]*acc[1][j] + acc[2][j]*acc[2][j] + acc[3][j]*acc[3][j];
      s += __shfl_xor(s, 16); q += __shfl_xor(q, 16);
      s += __shfl_xor(s, 32); q += __shfl_xor(q, 32);
      cs[j] = s; cq_[j] = q;
    }
    const int wv = t >> 6;
    if ((t & 48) == 0) {
#pragma unroll
      for (int j = 0; j < 4; ++j) { sred[wv][c0 + j] = cs[j]; qred[wv][c0 + j] = cq_[j]; }
    }
    __syncthreads();
    if (t < 64) {
      float s = sred[0][t] + sred[1][t] + sred[2][t] + sred[3][t];
      float q = qred[0][t] + qred[1][t] + qred[2][t] + qred[3][t];
      int shdw = (rt & 15) * 256;
      atomicAdd(&red_s[shdw + t], s);
      atomicAdd(&red_q[shdw + t], q);
    }
  }
}

// ---------------- l1_convb ----------------
__global__ __launch_bounds__(256) void l1_convb(
    const float* __restrict__ pcd,
    const int* __restrict__ idx,
    const float* __restrict__ WAT,
    const float* __restrict__ T,
    const u16* __restrict__ Wbh,
    const float* __restrict__ bb,
    const float* __restrict__ gA, const float* __restrict__ beA,
    const float* __restrict__ redA_s, const float* __restrict__ redA_q,
    float* __restrict__ redB_s, float* __restrict__ redB_q,
    float* __restrict__ hmax)
{
  __shared__ u16 Alds[64][72];
  __shared__ u16 Wlds[64][72];
  __shared__ float xyzs[64][4];
  __shared__ float was[3][64];
  __shared__ float scs[64], shs[64];
  __shared__ int ji[64];
  const int t = threadIdx.x;
  const int lane = t & 63, w = t >> 6;
  const int wr = w >> 1, wc = w & 1;
  const int cl = lane & 15, rq = lane >> 4;
  const int rt = blockIdx.x, b = blockIdx.y;
  const int R0 = rt * 64;
  const float* pb = pcd + (size_t)b * 12288;

  if (t < 64) ji[t] = idx[((size_t)b * 4096 + ((R0 + t) >> 5)) * KNN + ((R0 + t) & 31)];
  if (t < 192) was[t / 64][t & 63] = WAT[t];
  if (t >= 192) bn_from_red(t - 192, redA_s, redA_q, gA, beA, 1.f/1048576.f, scs, shs);
  for (int i = t; i < 64 * 8; i += 256) {
    int o = i >> 3, seg = i & 7;
    *(float4*)&Wlds[o][seg * 8] = *(const float4*)&Wbh[(size_t)o * 64 + seg * 8];
  }
  __syncthreads();
  if (t < 64) {
    const float* p = pb + (size_t)ji[t] * 3;
    xyzs[t][0] = p[0]; xyzs[t][1] = p[1]; xyzs[t][2] = p[2]; xyzs[t][3] = 0.f;
  }
  __syncthreads();

  for (int i = t; i < 64 * 8; i += 256) {
    int r = i >> 3, seg = i & 7;
    float px = xyzs[r][0], py = xyzs[r][1], pz = xyzs[r][2];
    const float* Tm = T + ((size_t)b * 4096 + (size_t)((R0 + r) >> 5)) * 64;
    half8 ov;
#pragma unroll
    for (int j2 = 0; j2 < 8; ++j2) {
      int c = seg * 8 + j2;
      float hh = Tm[c];
      hh = fmaf(px, was[0][c], hh);
      hh = fmaf(py, was[1][c], hh);
      hh = fmaf(pz, was[2][c], hh);
      ov[j2] = (_Float16)fmaxf(0.f, fmaf(hh, scs[c], shs[c]));
    }
    *(half8*)&Alds[r][seg * 8] = ov;
  }
  __syncthreads();

  f32x4 acc[2][2];
#pragma unroll
  for (int fr = 0; fr < 2; ++fr)
#pragma unroll
    for (int fc = 0; fc < 2; ++fc) {
      float bv = bb[wc * 32 + fc * 16 + cl];
#pragma unroll
      for (int r = 0; r < 4; ++r) acc[fr][fc][r] = bv;
    }

#pragma unroll
  for (int kk = 0; kk < 2; ++kk) {
    half8 af[2], bf[2];
#pragma unroll
    for (int fr = 0; fr < 2; ++fr)
      af[fr] = *(const half8*)&Alds[wr*32 + fr*16 + cl][kk*32 + rq*8];
#pragma unroll
    for (int fc = 0; fc < 2; ++fc)
      bf[fc] = *(const half8*)&Wlds[wc*32 + fc*16 + cl][kk*32 + rq*8];
#pragma unroll
    for (int fr = 0; fr < 2; ++fr)
#pragma unroll
      for (int fc = 0; fc < 2; ++fc)
        acc[fr][fc] = __builtin_amdgcn_mfma_f32_16x16x32_f16(af[fr], bf[fc], acc[fr][fc], 0, 0, 0);
  }

#pragma unroll
  for (int fc = 0; fc < 2; ++fc) {
    float s = 0.f, q = 0.f, mx = -3.4e38f;
#pragma unroll
    for (int fr = 0; fr < 2; ++fr)
#pragma unroll
      for (int r = 0; r < 4; ++r) {
        float v = acc[fr][fc][r];
        s += v; q += v * v; mx = fmaxf(mx, v);
      }
    s += __shfl_xor(s, 16); q += __shfl_xor(q, 16); mx = fmaxf(mx, __shfl_xor(mx, 16));
    s += __shfl_xor(s, 32); q += __shfl_xor(q, 32); mx = fmaxf(mx, __shfl_xor(mx, 32));
    if (rq == 0) {
      int col = wc * 32 + fc * 16 + cl;
      int shdw = (rt & 15) * 256;
      atomicAdd(&redB_s[shdw + col], s);
      atomicAdd(&redB_q[shdw + col], q);
      hmax[((size_t)b * 4096 + (size_t)(rt * 2 + wr)) * 64 + col] = mx;
    }
  }
}

// ---------------- conv_a MFMA (L2/L3 edge): f16 gather, fp8 H out, fused bn1 stats ----------------
template<int CM, int KPAD>
__global__ __launch_bounds__(256) void conv_a_mfma(
    const u16* __restrict__ F, int frs, size_t fbstride,
    const int* __restrict__ idx, int idxstride,
    const u16* __restrict__ Wh,
    const float* __restrict__ T,
    u32* __restrict__ H32,
    float* __restrict__ red_s, float* __restrict__ red_q,
    int M)
{
  constexpr int FC = CM / 32;
  __shared__ u16 Alds[64][72];
  __shared__ u16 Wlds[CM][72];
  __shared__ int ji[64];
  const int t = threadIdx.x;
  const int lane = t & 63, w = t >> 6;
  const int wr = w >> 1, wc = w & 1;
  const int cl = lane & 15, rq = lane >> 4;
  const int rt = blockIdx.x, b = blockIdx.y;
  const int R0 = rt * 64;
  const u16* Fb = F + (size_t)b * fbstride;

  if (t < 64) ji[t] = idx[((size_t)b * idxstride + ((R0 + t) >> 5)) * KNN + ((R0 + t) & 31)];

  f32x4 acc[2][FC];
#pragma unroll
  for (int fr = 0; fr < 2; ++fr)
#pragma unroll
    for (int fc = 0; fc < FC; ++fc) {
      int col = wc * (CM/2) + fc * 16 + cl;
#pragma unroll
      for (int r = 0; r < 4; ++r) {
        int row = R0 + wr*32 + fr*16 + rq*4 + r;
        acc[fr][fc][r] = T[((size_t)b * M + (row >> 5)) * CM + col];
      }
    }
  __syncthreads();

  for (int k0 = 0; k0 < KPAD; k0 += 64) {
    if (k0) __syncthreads();
    for (int i = t; i < 64 * 16; i += 256) {
      int r = i >> 4, seg = i & 15;
      int k = k0 + seg * 4;
      ushort4 s = {0,0,0,0};
      if (k < frs) s = *(const ushort4*)&Fb[(size_t)ji[r] * frs + k];
      *(ushort4*)&Alds[r][seg * 4] = s;
    }
    for (int i = t; i < CM * 8; i += 256) {
      int o = i >> 3, seg = i & 7;
      *(float4*)&Wlds[o][seg * 8] = *(const float4*)&Wh[(size_t)o * KPAD + k0 + seg * 8];
    }
    __syncthreads();

#pragma unroll
    for (int kk = 0; kk < 2; ++kk) {
      half8 af[2], bf[FC];
#pragma unroll
      for (int fr = 0; fr < 2; ++fr)
        af[fr] = *(const half8*)&Alds[wr*32 + fr*16 + cl][kk*32 + rq*8];
#pragma unroll
      for (int fc = 0; fc < FC; ++fc)
        bf[fc] = *(const half8*)&Wlds[wc*(CM/2) + fc*16 + cl][kk*32 + rq*8];
#pragma unroll
      for (int fr = 0; fr < 2; ++fr)
#pragma unroll
        for (int fc = 0; fc < FC; ++fc)
          acc[fr][fc] = __builtin_amdgcn_mfma_f32_16x16x32_f16(af[fr], bf[fc], acc[fr][fc], 0, 0, 0);
    }
  }

  u32* Hb4 = H32 + ((size_t)b * ((size_t)M * KNN / 4) + (size_t)(R0 >> 2)) * CM;
#pragma unroll
  for (int fr = 0; fr < 2; ++fr)
#pragma unroll
    for (int fc = 0; fc < FC; ++fc) {
      int col = wc*(CM/2) + fc*16 + cl;
      u32 v = __builtin_amdgcn_cvt_pk_fp8_f32(acc[fr][fc][0], acc[fr][fc][1], 0, false);
      v = __builtin_amdgcn_cvt_pk_fp8_f32(acc[fr][fc][2], acc[fr][fc][3], v, true);
      Hb4[(size_t)(wr*8 + fr*4 + rq) * CM + col] = v;
    }

#pragma unroll
  for (int fc = 0; fc < FC; ++fc) {
    float s = 0.f, q = 0.f;
#pragma unroll
    for (int fr = 0; fr < 2; ++fr)
#pragma unroll
      for (int r = 0; r < 4; ++r) {
        float v = acc[fr][fc][r];
        s += v; q += v * v;
      }
    s += __shfl_xor(s, 16); q += __shfl_xor(q, 16);
    s += __shfl_xor(s, 32); q += __shfl_xor(q, 32);
    if (rq == 0) {
      int col = wc*(CM/2) + fc*16 + cl;
      int shdw = (rt & 15) * 256;
      atomicAdd(&red_s[shdw + col], s);
      atomicAdd(&red_q[shdw + col], q);
    }
  }
}

// ---------------- conv_b MFMA fused: 128 rows/block ----------------
template<int CM>
__global__ __launch_bounds__(512) void conv_b_fused(
    const u32* __restrict__ H32,
    const u16* __restrict__ Wh,
    const float* __restrict__ bb,
    const float* __restrict__ gA, const float* __restrict__ beA,
    const float* __restrict__ redA_s, const float* __restrict__ redA_q, float invcnt,
    float* __restrict__ redB_s, float* __restrict__ redB_q,
    float* __restrict__ hmax,
    int Mrows)
{
  constexpr int FC = CM / 32;
  __shared__ u16 Alds[128][72];
  __shared__ u16 Wlds[CM][72];
  __shared__ float scs[CM], shs[CM];
  const int t = threadIdx.x;
  const int lane = t & 63, w = t >> 6;
  const int wr = w >> 1;
  const int wc = w & 1;
  const int cl = lane & 15, rq = lane >> 4;
  const int rt = blockIdx.x, b = blockIdx.y;
  const u32* Hb4 = H32 + ((size_t)b * ((size_t)Mrows / 4) + (size_t)(rt * 32)) * CM;

  for (int i = t; i < CM; i += 512) bn_from_red(i, redA_s, redA_q, gA, beA, invcnt, scs, shs);

  f32x4 acc[2][FC];
#pragma unroll
  for (int fr = 0; fr < 2; ++fr)
#pragma unroll
    for (int fc = 0; fc < FC; ++fc) {
      float bv = bb[wc * (CM/2) + fc * 16 + cl];
#pragma unroll
      for (int r = 0; r < 4; ++r) acc[fr][fc][r] = bv;
    }
  __syncthreads();

  for (int k0 = 0; k0 < CM; k0 += 64) {
    if (k0) __syncthreads();
    for (int i = t; i < 128 * 8; i += 512) {
      int r = i >> 3, seg = i & 7;
      int rg = r >> 2, sh8 = (r & 3) * 8;
      const u32* hp = Hb4 + (size_t)rg * CM + k0 + seg * 8;
      half8 ov;
#pragma unroll
      for (int j = 0; j < 8; ++j) {
        float v = __builtin_amdgcn_cvt_f32_fp8((hp[j] >> sh8) & 0xffu, 0);
        int c = k0 + seg * 8 + j;
        v = fmaxf(0.f, fmaf(v, scs[c], shs[c]));
        ov[j] = (_Float16)v;
      }
      *(half8*)&Alds[r][seg * 8] = ov;
    }
    for (int i = t; i < CM * 8; i += 512) {
      int o = i >> 3, seg = i & 7;
      *(float4*)&Wlds[o][seg * 8] = *(const float4*)&Wh[(size_t)o * CM + k0 + seg * 8];
    }
    __syncthreads();

#pragma unroll
    for (int kk = 0; kk < 2; ++kk) {
      half8 af[2], bf[FC];
#pragma unroll
      for (int fr = 0; fr < 2; ++fr)
        af[fr] = *(const half8*)&Alds[wr*32 + fr*16 + cl][kk*32 + rq*8];
#pragma unroll
      for (int fc = 0; fc < FC; ++fc)
        bf[fc] = *(const half8*)&Wlds[wc*(CM/2) + fc*16 + cl][kk*32 + rq*8];
#pragma unroll
      for (int fr = 0; fr < 2; ++fr)
#pragma unroll
        for (int fc = 0; fc < FC; ++fc)
          acc[fr][fc] = __builtin_amdgcn_mfma_f32_16x16x32_f16(af[fr], bf[fc], acc[fr][fc], 0, 0, 0);
    }
  }

#pragma unroll
  for (int fc = 0; fc < FC; ++fc) {
    float s = 0.f, q = 0.f, mx = -3.4e38f;
#pragma unroll
    for (int fr = 0; fr < 2; ++fr)
#pragma unroll
      for (int r = 0; r < 4; ++r) {
        float v = acc[fr][fc][r];
        s += v; q += v * v; mx = fmaxf(mx, v);
      }
    s += __shfl_xor(s, 16); q += __shfl_xor(q, 16); mx = fmaxf(mx, __shfl_xor(mx, 16));
    s += __shfl_xor(s, 32); q += __shfl_xor(q, 32); mx = fmaxf(mx, __shfl_xor(mx, 32));
    if (rq == 0) {
      int col = wc*(CM/2) + fc*16 + cl;
      int shdw = (rt & 15) * 256;
      atomicAdd(&redB_s[shdw + col], s);
      atomicAdd(&redB_q[shdw + col], q);
      hmax[((size_t)b * (Mrows >> 5) + (size_t)(rt * 4 + wr)) * CM + col] = mx;
    }
  }
}

// ---------------- bn2(inline) + relu on max -> f16 feature buffer (+ xyz append) ----------------
__global__ __launch_bounds__(256) void bnrelu_fb(const float* __restrict__ hm,
    const float* __restrict__ gB, const float* __restrict__ beB,
    const float* __restrict__ redB_s, const float* __restrict__ redB_q, float invcnt,
    const float* __restrict__ pcd,
    u16* __restrict__ fout, int CM, int fostride, size_t fobstride, int M) {
  __shared__ float scs[256], shs[256];
  for (int o = threadIdx.x; o < CM; o += 256) bn_from_red(o, redB_s, redB_q, gB, beB, invcnt, scs, shs);
  __syncthreads();
  int i = blockIdx.x * 256 + threadIdx.x;
  int cq = CM >> 2;
  int total = B8 * M * cq;
  if (i >= total) return;
  int c4 = i % cq; int r = i / cq;
  int b = r / M, m = r - b * M;
  float4 v = *(const float4*)&hm[((size_t)b * M + m) * CM + c4 * 4];
  int c = c4 * 4;
  ushort4 o;
  o.x = f2h_u(fmaxf(0.f, fmaf(v.x, scs[c],   shs[c])));
  o.y = f2h_u(fmaxf(0.f, fmaf(v.y, scs[c+1], shs[c+1])));
  o.z = f2h_u(fmaxf(0.f, fmaf(v.z, scs[c+2], shs[c+2])));
  o.w = f2h_u(fmaxf(0.f, fmaf(v.w, scs[c+3], shs[c+3])));
  u16* op = fout + (size_t)b * fobstride + (size_t)m * fostride;
  *(ushort4*)(op + c) = o;
  if (pcd && c4 == 0) {
    const float* p = pcd + ((size_t)b * 4096 + m) * 3;
    half8 xz;
    xz[0] = (_Float16)p[0]; xz[1] = (_Float16)p[1]; xz[2] = (_Float16)p[2];
    xz[3] = (_Float16)0.f; xz[4] = (_Float16)0.f; xz[5] = (_Float16)0.f;
    xz[6] = (_Float16)0.f; xz[7] = (_Float16)0.f;
    *(half8*)(op + CM) = xz;
  }
}

// ---------------- fused L3 epilogue: bn2+relu(HMAX) -> out3/out1 FC + xyz/idx ----------------
__global__ __launch_bounds__(256) void fc_fused(
    const float* __restrict__ hm,      // HMAX [b][1024][256] fp32 (raw h2 max)
    const float* __restrict__ gB, const float* __restrict__ beB,
    const float* __restrict__ redB_s, const float* __restrict__ redB_q, float invcnt,
    const float* __restrict__ fcW, const float* __restrict__ fcb,
    const float* __restrict__ pcd,
    float* __restrict__ out0, float* __restrict__ out1,
    float* __restrict__ out2, float* __restrict__ out3) {
  __shared__ float tile[32 * 257];
  __shared__ float scs[256], shs[256];
  const int t = threadIdx.x, b = blockIdx.x, n0 = blockIdx.y * 32;
  bn_from_red(t, redB_s, redB_q, gB, beB, invcnt, scs, shs);
  __syncthreads();
  for (int i = t; i < 32 * 64; i += 256) {
    int n = i >> 6, c4 = i & 63;
    float4 v = *(const float4*)&hm[((size_t)b * 1024 + n0 + n) * 256 + c4 * 4];
    int c = c4 * 4;
    float* tp = &tile[n * 257 + c];
    tp[0] = fmaxf(0.f, fmaf(v.x, scs[c],   shs[c]));
    tp[1] = fmaxf(0.f, fmaf(v.y, scs[c+1], shs[c+1]));
    tp[2] = fmaxf(0.f, fmaf(v.z, scs[c+2], shs[c+2]));
    tp[3] = fmaxf(0.f, fmaf(v.w, scs[c+3], shs[c+3]));
  }
  __syncthreads();
  const int n = t & 31, og = t >> 5;
#pragma unroll
  for (int ci = 0; ci < 32; ++ci) {
    int c = og * 32 + ci;
    out3[((size_t)b * 256 + c) * 1024 + n0 + n] = tile[n * 257 + c];
  }
#pragma unroll
  for (int oi = 0; oi < 16; ++oi) {
    int o = og * 16 + oi;
    float acc = fcb[o];
    const float* w = fcW + (size_t)o * 256;
#pragma unroll 4
    for (int c = 0; c < 256; ++c) acc = fmaf(tile[n * 257 + c], w[c], acc);
    out1[((size_t)b * 128 + o) * 1024 + n0 + n] = acc;
  }
  if (t < 32) {
    int nn = n0 + t;
    const float* p = pcd + ((size_t)b * 4096 + nn) * 3;
    float* o0 = out0 + ((size_t)b * 1024 + nn) * 3;
    o0[0] = p[0]; o0[1] = p[1]; o0[2] = p[2];
    out2[(size_t)b * 1024 + nn] = (float)nn;
  }
}

// ---------------- host ----------------
extern "C" void kernel_launch(void* const* d_in, const int* in_sizes, int n_in,
                              void* d_out, int out_size, void* d_ws, size_t ws_size,
                              hipStream_t stream) {
  (void)in_sizes; (void)n_in; (void)out_size; (void)ws_size;
  const float* pcd = (const float*)d_in[0];
  const float* W1a = (const float*)d_in[1];  const float* b1a = (const float*)d_in[2];
  const float* g1a = (const float*)d_in[3];  const float* be1a= (const float*)d_in[4];
  const float* W1b = (const float*)d_in[5];  const float* b1b = (const float*)d_in[6];
  const float* g1b = (const float*)d_in[7];  const float* be1b= (const float*)d_in[8];
  const float* W2a = (const float*)d_in[9];  const float* b2a = (const float*)d_in[10];
  const float* g2a = (const float*)d_in[11]; const float* be2a= (const float*)d_in[12];
  const float* W2b = (const float*)d_in[13]; const float* b2b = (const float*)d_in[14];
  const float* g2b = (const float*)d_in[15]; const float* be2b= (const float*)d_in[16];
  const float* W3a = (const float*)d_in[17]; const float* b3a = (const float*)d_in[18];
  const float* g3a = (const float*)d_in[19]; const float* be3a= (const float*)d_in[20];
  const float* W3b = (const float*)d_in[21]; const float* b3b = (const float*)d_in[22];
  const float* g3b = (const float*)d_in[23]; const float* be3b= (const float*)d_in[24];
  const float* fcW = (const float*)d_in[25]; const float* fcb = (const float*)d_in[26];

  u16* FB2h = (u16*)d_ws;                       // 8*4096*72
  u16* FB3h = FB2h + 2359296;                   // 8*2048*136
  float* wsf = (float*)(FB3h + 2228224);
  float* TBUF= wsf;                             // 8*4096*64
  float* RED = TBUF + 2097152;                  // 6 x 8192
  float* R1A = RED;          float* R1B = RED + 8192;
  float* R2A = RED + 16384;  float* R2B = RED + 24576;
  float* R3A = RED + 32768;  float* R3B = RED + 40960;
  float* WAT1 = RED + 49152;
  float* WBT1 = WAT1 + 256;
  float* WBT2 = WBT1 + 256;
  float* WBT3 = WBT2 + 8704;
  float* HMAX = WBT3 + 33792;                   // 8*4096*64
  int* IDX1 = (int*)(HMAX + 2097152);           // 8*4096*32
  int* IDX3 = IDX1 + (size_t)8 * 4096 * 32;     // 8*1024*32
  u32* H32  = (u32*)(IDX3 + (size_t)8 * 1024 * 32); // 64 MiB fp8 H
  u16* WBH1 = (u16*)(H32 + 16777216);
  u16* WAH2 = WBH1 + 4096;
  u16* WBH2 = WAH2 + 16384;
  u16* WAH3 = WBH2 + 16384;
  u16* WBH3 = WAH3 + 49152;

  float* out0 = (float*)d_out;
  float* out1 = out0 + 24576;
  float* out2 = out1 + 1048576;
  float* out3 = out2 + 8192;

  prep_all<<<64, 256, 0, stream>>>(W1a, W1b, W2a, W2b, W3a, W3b, RED,
                                   WAT1, WBT1, WBH1, WBT2, WAH2, WBH2, WBT3, WAH3, WBH3);

  // ================ merged KNN: L1 (blocks 0..1023) + L3 (blocks 1024..1279) ================
  knn_dual<<<dim3(1280, 8), 256, 0, stream>>>(pcd, IDX1, IDX3);

  // ================ Layer 1: C2=3, CM=64, M=4096, N=4096 ================
  conv_a_gemm<3,64,0,0><<<dim3(64,1,8),256,0,stream>>>(pcd,3,(size_t)12288,nullptr,WBT1,b1a,nullptr,TBUF,nullptr,nullptr,4096);
  conv_a_gemm<3,64,1,0><<<dim3(2048,1,8),256,0,stream>>>(pcd,3,(size_t)12288,IDX1,WAT1,nullptr,TBUF,nullptr,R1A,R1A+4096,4096);
  l1_convb<<<dim3(2048,8),256,0,stream>>>(pcd,IDX1,WAT1,TBUF,WBH1,b1b,g1a,be1a,R1A,R1A+4096,R1B,R1B+4096,HMAX);
  bnrelu_fb<<<2048,256,0,stream>>>(HMAX,g1b,be1b,R1B,R1B+4096,1.f/1048576.f,pcd,FB2h,64,72,(size_t)294912,4096);

  // ================ Layer 2: C2=67, CM=128, M=2048, N=4096  (IDX2 == IDX1[:, :2048]) ================
  conv_a_gemm<67,128,0,1><<<dim3(32,2,8),256,0,stream>>>(FB2h,72,(size_t)294912,nullptr,WBT2,b2a,nullptr,TBUF,nullptr,nullptr,2048);
  conv_a_mfma<128,128><<<dim3(1024,8),256,0,stream>>>(FB2h,72,(size_t)294912,IDX1,4096,WAH2,TBUF,H32,R2A,R2A+4096,2048);
  conv_b_fused<128><<<dim3(512,8),512,0,stream>>>(H32,WBH2,b2b,g2a,be2a,R2A,R2A+4096,1.f/524288.f,R2B,R2B+4096,HMAX,2048*32);
  bnrelu_fb<<<2048,256,0,stream>>>(HMAX,g2b,be2b,R2B,R2B+4096,1.f/524288.f,pcd,FB3h,128,136,(size_t)278528,2048);

  // ================ Layer 3: C2=131, CM=256, M=1024, N=2048 ================
  conv_a_gemm<131,256,0,1><<<dim3(16,4,8),256,0,stream>>>(FB3h,136,(size_t)278528,nullptr,WBT3,b3a,nullptr,TBUF,nullptr,nullptr,1024);
  conv_a_mfma<256,192><<<dim3(512,8),256,0,stream>>>(FB3h,136,(size_t)278528,IDX3,1024,WAH3,TBUF,H32,R3A,R3A+4096,1024);
  conv_b_fused<256><<<dim3(256,8),512,0,stream>>>(H32,WBH3,b3b,g3a,be3a,R3A,R3A+4096,1.f/262144.f,R3B,R3B+4096,HMAX,1024*32);

  // ================ fused L3 epilogue + outputs ================
  fc_fused<<<dim3(8, 32), 256, 0, stream>>>(HMAX,g3b,be3b,R3B,R3B+4096,1.f/262144.f,fcW,fcb,pcd,out0,out1,out2,out3);
}